// Round 7
// baseline (366.180 us; speedup 1.0000x reference)
//
#include <hip/hip_runtime.h>
#include <hip/hip_bf16.h>

typedef __attribute__((ext_vector_type(4))) float f32x4;
typedef __attribute__((ext_vector_type(8))) short bf16x8;
typedef __attribute__((ext_vector_type(4))) short s16x4;

#define C_DIM 512
#define N_PIX 2304
#define N_BATCH 8
#define ATT_SCALE 0.04419417382415922f
#define NJB 9                       // N_PIX / 256 (s-kernel j-tiles)

typedef __attribute__((address_space(3))) unsigned int lds_u32;
typedef const __attribute__((address_space(1))) unsigned int glob_u32;

__device__ __forceinline__ void gl2lds16(const __hip_bfloat16* g, __hip_bfloat16* l)
{
    __builtin_amdgcn_global_load_lds((glob_u32*)g, (lds_u32*)l, 16, 0, 0);
}

#define GBAR() __builtin_amdgcn_s_barrier()
#define GVM0() asm volatile("s_waitcnt vmcnt(0)" ::: "memory")

// ===========================================================================
// ALGEBRAIC FOLDS (kept from round-6):
//  scores/sc = Xl·(Wq^T Wk)·Xg^T + v[m]  (row-constant terms cancel in softmax)
//    matT[c2][c1] = sum_o Wk[o,c2]Wq[o,c1];  T = gemm_bt(Xlt, matT)
//    v[b,m] = sum_c glox[b,c,m]·wv[c], wv[c] = sum_o Wk[o,c]bq[o]
//  Vp = (Wo·Wv)·Xg^T + bov:  Wov[o][c] = sum_o2 Wo[o,o2]Wv[o2,c], bov = Wo·bv
// ROUND-7: wmix eliminated — matT/Wov/v/bov computed in FRONT-LOADED prep
// blocks directly from fp32 inputs (order-independent), hidden under the
// 4608 transpose blocks. 4 launches total. pv_out upgraded to 128x128 tile.
// ===========================================================================

// ---------------------------------------------------------------------------
// s_only: 256x256 8-phase (round-1-proven structure), S-tiles only (648 blks).
// Pu[n,m] = exp(SC*(sum_c T[n,c]Xgt[m,c] + v[m])), rp row-sum partials.
// ---------------------------------------------------------------------------

#define BAR()  __builtin_amdgcn_s_barrier()
#define LGK0() asm volatile("s_waitcnt lgkmcnt(0)" ::: "memory")
#define VM4()  asm volatile("s_waitcnt vmcnt(4)" ::: "memory")
#define VM0()  asm volatile("s_waitcnt vmcnt(0)" ::: "memory")
#define PRIO(p) __builtin_amdgcn_s_setprio(p)

#define STAGE_A(dd, hh, tk) do { \
    _Pragma("unroll") \
    for (int ss = 0; ss < 2; ++ss) { \
        const int ur0 = wave * 16 + ss * 8; \
        const int row0 = ((ur0 >> 6) << 7) + (hh) * 64 + (ur0 & 63); \
        gl2lds16(gA + (size_t)row0 * C_DIM + (tk) * 64, \
                 (__hip_bfloat16*)&LA[dd][row0 * 64]); \
    } } while (0)

#define STAGE_B(dd, bb, tk) do { \
    _Pragma("unroll") \
    for (int ss = 0; ss < 2; ++ss) { \
        const int ur0 = wave * 16 + ss * 8; \
        const int row0 = ((ur0 >> 5) << 6) + (bb) * 32 + (ur0 & 31); \
        gl2lds16(gB + (size_t)row0 * C_DIM + (tk) * 64, \
                 (__hip_bfloat16*)&LB[dd][row0 * 64]); \
    } } while (0)

#define LOAD_A(dd, hh) do { \
    _Pragma("unroll") \
    for (int tt = 0; tt < 4; ++tt) { \
        const int rb = (wr * 128 + (hh) * 64 + tt * 16 + fr) * 64; \
        _Pragma("unroll") \
        for (int kk = 0; kk < 2; ++kk) \
            aF[tt][kk] = *(const bf16x8*)(&LA[dd][rb + (((kk * 4 + fq) ^ sw) << 3)]); \
    } } while (0)

#define LOAD_B(dd, bb, dst) do { \
    _Pragma("unroll") \
    for (int s2 = 0; s2 < 2; ++s2) { \
        const int rb = (wc * 64 + (bb) * 32 + s2 * 16 + fr) * 64; \
        _Pragma("unroll") \
        for (int kk = 0; kk < 2; ++kk) \
            dst[s2][kk] = *(const bf16x8*)(&LB[dd][rb + (((kk * 4 + fq) ^ sw) << 3)]); \
    } } while (0)

#define MFMA_Q(HH, BB, bsrc) do { \
    _Pragma("unroll") \
    for (int tt = 0; tt < 4; ++tt) \
    _Pragma("unroll") \
    for (int s2 = 0; s2 < 2; ++s2) \
    _Pragma("unroll") \
    for (int kk = 0; kk < 2; ++kk) \
        acc[(HH) * 4 + tt][(BB) * 2 + s2] = __builtin_amdgcn_mfma_f32_16x16x32_bf16( \
            aF[tt][kk], bsrc[s2][kk], acc[(HH) * 4 + tt][(BB) * 2 + s2], 0, 0, 0); \
    } while (0)

template<int NS>
__global__ __launch_bounds__(512, 2)
void s_only(const __hip_bfloat16* __restrict__ Tm, const __hip_bfloat16* __restrict__ Xgt,
            __hip_bfloat16* __restrict__ Pu, float* __restrict__ rp,
            const float* __restrict__ vvec, int bz_off, long sPu)
{
    __shared__ __hip_bfloat16 LA[2][256 * 64];
    __shared__ __hip_bfloat16 LB[2][256 * 64];

    const int lin = blockIdx.x;
    const int bz  = lin % NS + bz_off;
    const int t   = lin / NS;
    const int ib  = t / 9;
    const int jb  = t % 9;
    const long sQ = (long)N_PIX * C_DIM;

    const __hip_bfloat16* A = Tm  + (size_t)bz * sQ;
    const __hip_bfloat16* B = Xgt + (size_t)bz * sQ;
    __hip_bfloat16* D = Pu + (size_t)bz * (size_t)sPu;

    const int i0 = ib * 256;
    const int j0 = jb * 256;

    const int tid  = threadIdx.x;
    const int lane = tid & 63;
    const int wave = tid >> 6;

    const int lrow = lane >> 3;
    const int lcs  = (lane & 7) ^ lrow;           // XOR chunk swizzle (store side)
    const __hip_bfloat16* gA = A + (size_t)(i0 + lrow) * C_DIM + lcs * 8;
    const __hip_bfloat16* gB = B + (size_t)(j0 + lrow) * C_DIM + lcs * 8;

    const int fr = lane & 15;
    const int fq = lane >> 4;
    const int sw = fr & 7;                        // row&7 on read side
    const int wr = wave >> 2;                     // 0..1 (row wave)
    const int wc = wave & 3;                      // 0..3 (col wave)

    f32x4 acc[8][4];
#pragma unroll
    for (int a = 0; a < 8; ++a)
#pragma unroll
        for (int b = 0; b < 4; ++b)
            acc[a][b] = (f32x4){0.f, 0.f, 0.f, 0.f};

    bf16x8 aF[4][2], bF0[2][2], bF1[2][2];

    // prologue: tile0 (4 halves) + tile1 {A0,B1}; vmcnt(4) -> tile0 landed
    STAGE_A(0, 0, 0); STAGE_B(0, 0, 0); STAGE_B(0, 1, 0); STAGE_A(0, 1, 0);
    STAGE_A(1, 0, 1); STAGE_B(1, 1, 1);
    VM4();
    BAR();

    for (int kt = 0; kt < 6; ++kt) {
        const int d = kt & 1, e = d ^ 1;
        LOAD_A(d, 0); LOAD_B(d, 0, bF0);
        STAGE_A(e, 1, kt + 1);
        BAR(); LGK0();
        PRIO(1); MFMA_Q(0, 0, bF0); PRIO(0);
        BAR();
        LOAD_B(d, 1, bF1);
        STAGE_B(e, 0, kt + 1);
        BAR(); LGK0();
        PRIO(1); MFMA_Q(0, 1, bF1); PRIO(0);
        BAR();
        LOAD_A(d, 1);
        STAGE_A(d, 0, kt + 2);
        BAR(); LGK0();
        PRIO(1); MFMA_Q(1, 1, bF1); PRIO(0);
        BAR();
        STAGE_B(d, 1, kt + 2);
        VM4();
        BAR();
        PRIO(1); MFMA_Q(1, 0, bF0); PRIO(0);
        BAR();
    }
    {   // K-tile 6 (buf 0): stage only tile-7 {A1,B0}
        LOAD_A(0, 0); LOAD_B(0, 0, bF0);
        STAGE_A(1, 1, 7);
        BAR(); LGK0();
        PRIO(1); MFMA_Q(0, 0, bF0); PRIO(0);
        BAR();
        LOAD_B(0, 1, bF1);
        STAGE_B(1, 0, 7);
        BAR(); LGK0();
        PRIO(1); MFMA_Q(0, 1, bF1); PRIO(0);
        BAR();
        LOAD_A(0, 1);
        BAR(); LGK0();
        PRIO(1); MFMA_Q(1, 1, bF1); PRIO(0);
        BAR();
        VM0();
        BAR();
        PRIO(1); MFMA_Q(1, 0, bF0); PRIO(0);
        BAR();
    }
    {   // K-tile 7 (buf 1): no staging
        LOAD_A(1, 0); LOAD_B(1, 0, bF0);
        BAR(); LGK0();
        PRIO(1); MFMA_Q(0, 0, bF0); PRIO(0);
        BAR();
        LOAD_B(1, 1, bF1);
        BAR(); LGK0();
        PRIO(1); MFMA_Q(0, 1, bF1); PRIO(0);
        BAR();
        LOAD_A(1, 1);
        BAR(); LGK0();
        PRIO(1); MFMA_Q(1, 1, bF1); PRIO(0);
        BAR();
        PRIO(1); MFMA_Q(1, 0, bF0); PRIO(0);
    }

    // epilogue: exp(SC*(acc + v[m])), rp partials
    float vb[4];
#pragma unroll
    for (int b = 0; b < 4; ++b)
        vb[b] = vvec[(size_t)bz * N_PIX + j0 + wc * 64 + b * 16 + fr];

    float rpart[8][4];
#pragma unroll
    for (int a = 0; a < 8; ++a)
#pragma unroll
        for (int r = 0; r < 4; ++r)
            rpart[a][r] = 0.f;
#pragma unroll
    for (int a = 0; a < 8; ++a) {
        const int grow = i0 + wr * 128 + a * 16 + fq * 4;
#pragma unroll
        for (int b = 0; b < 4; ++b) {
            const int col = j0 + wc * 64 + b * 16 + fr;
#pragma unroll
            for (int r = 0; r < 4; ++r) {
                float v = __expf(ATT_SCALE * (acc[a][b][r] + vb[b]));
                rpart[a][r] += v;
                D[(size_t)(grow + r) * N_PIX + col] = __float2bfloat16(v);
            }
        }
    }
#pragma unroll
    for (int m = 1; m < 16; m <<= 1)
#pragma unroll
        for (int a = 0; a < 8; ++a)
#pragma unroll
            for (int r = 0; r < 4; ++r)
                rpart[a][r] += __shfl_xor(rpart[a][r], m);
    float* rsl = (float*)&LA[0][0];
    __syncthreads();
    if (fr == 0) {
#pragma unroll
        for (int a = 0; a < 8; ++a)
#pragma unroll
            for (int r = 0; r < 4; ++r)
                rsl[wave * 128 + a * 16 + fq * 4 + r] = rpart[a][r];
    }
    __syncthreads();
    if (tid < 256) {
        const int wr2 = tid >> 7, rl = tid & 127;
        float s = rsl[(wr2 * 4 + 0) * 128 + rl] + rsl[(wr2 * 4 + 1) * 128 + rl]
                + rsl[(wr2 * 4 + 2) * 128 + rl] + rsl[(wr2 * 4 + 3) * 128 + rl];
        rp[((size_t)jb * N_BATCH + bz) * N_PIX + i0 + tid] = s;
    }
}

#undef STAGE_A
#undef STAGE_B
#undef LOAD_A
#undef LOAD_B
#undef MFMA_Q
#undef BAR
#undef LGK0
#undef VM4
#undef VM0
#undef PRIO

// ---------------------------------------------------------------------------
// PV + output, ROUND-7: 128x128 tile (i=o 4 tiles, j=n 18 tiles), K=2304
// (36 K-tiles), grid NS*72 i-fast. Double MFMA density vs the 64x128 tile.
// out[o,n] = rinv[n]*sum_m Vp[o,m]Pu[n,m] + bo[o].
// ---------------------------------------------------------------------------

#define PV_STAGE(ee, tk) do { \
    _Pragma("unroll") \
    for (int ss = 0; ss < 4; ++ss) { \
        gl2lds16(ga + (size_t)ss * 8 * N_PIX + (tk) * 64, \
                 laA + (ee) * (128 * 64) + ss * 8 * 64); \
        gl2lds16(gb + (size_t)ss * 8 * N_PIX + (tk) * 64, \
                 laB + (ee) * (128 * 64) + ss * 8 * 64); \
    } } while (0)

#define PV_COMP(dd) do { \
    _Pragma("unroll") \
    for (int kk = 0; kk < 2; ++kk) { \
        bf16x8 af[4], bfr[4]; \
        const int ca = ((kk * 4 + fq) ^ sw) << 3; \
        _Pragma("unroll") \
        for (int tt = 0; tt < 4; ++tt) { \
            af[tt]  = *(const bf16x8*)(&As[dd][(wi + tt * 16 + fr) * 64 + ca]); \
            bfr[tt] = *(const bf16x8*)(&Bs[dd][(wj + tt * 16 + fr) * 64 + ca]); \
        } \
        _Pragma("unroll") \
        for (int a = 0; a < 4; ++a) \
        _Pragma("unroll") \
        for (int b = 0; b < 4; ++b) \
            acc[a][b] = __builtin_amdgcn_mfma_f32_16x16x32_bf16( \
                af[a], bfr[b], acc[a][b], 0, 0, 0); \
    } } while (0)

template<int NS>
__global__ __launch_bounds__(256)
void pv_out(const __hip_bfloat16* __restrict__ Vp, const __hip_bfloat16* __restrict__ Pu,
            float* __restrict__ out, const float* __restrict__ bo,
            const float* __restrict__ rp, int bz_off, long sPu)
{
    __shared__ __hip_bfloat16 As[2][128 * 64];
    __shared__ __hip_bfloat16 Bs[2][128 * 64];

    const int lin = blockIdx.x;
    const int bz  = lin % NS + bz_off;
    const int t   = lin / NS;
    const int ib  = t % 4;       // i-fast: consecutive blocks share Pu j-tile
    const int jb  = t / 4;
    const int i0  = ib * 128;
    const int j0  = jb * 128;

    const long sCN = (long)C_DIM * N_PIX;
    const __hip_bfloat16* A = Vp + (size_t)bz * sCN;         // [C,N] lda=N
    const __hip_bfloat16* B = Pu + (size_t)bz * (size_t)sPu; // [N,N] ldb=N
    float* D = out + (size_t)bz * sCN;

    const int tid  = threadIdx.x;
    const int lane = tid & 63;
    const int wave = tid >> 6;

    const int lrow = lane >> 3;
    const int lcs  = (lane & 7) ^ lrow;
    const __hip_bfloat16* ga = A + (size_t)(i0 + wave * 32 + lrow) * N_PIX + lcs * 8;
    const __hip_bfloat16* gb = B + (size_t)(j0 + wave * 32 + lrow) * N_PIX + lcs * 8;
    __hip_bfloat16* laA = &As[0][wave * 32 * 64];
    __hip_bfloat16* laB = &Bs[0][wave * 32 * 64];

    const int fr = lane & 15;
    const int fq = lane >> 4;
    const int sw = fr & 7;
    const int wi = (wave >> 1) * 64;
    const int wj = (wave & 1) * 64;

    f32x4 acc[4][4];
#pragma unroll
    for (int a = 0; a < 4; ++a)
#pragma unroll
        for (int b = 0; b < 4; ++b)
            acc[a][b] = (f32x4){0.f, 0.f, 0.f, 0.f};

    PV_STAGE(0, 0);
    GVM0(); GBAR();

#pragma unroll 1
    for (int kt = 0; kt < 34; kt += 2) {
        PV_STAGE(1, kt + 1);
        PV_COMP(0);
        GVM0(); GBAR();
        PV_STAGE(0, kt + 2);
        PV_COMP(1);
        GVM0(); GBAR();
    }
    PV_STAGE(1, 35);
    PV_COMP(0);
    GVM0(); GBAR();
    PV_COMP(1);

    const int orow = fq * 4;
    float rjv[4];
#pragma unroll
    for (int b = 0; b < 4; ++b) {
        int j = j0 + wj + b * 16 + fr;
        float s = 0.f;
#pragma unroll
        for (int jj = 0; jj < NJB; ++jj)
            s += rp[((size_t)jj * N_BATCH + bz) * N_PIX + j];
        rjv[b] = 1.f / s;
    }

#pragma unroll
    for (int a = 0; a < 4; ++a) {
        int ibx = i0 + wi + a * 16 + orow;
#pragma unroll
        for (int r = 0; r < 4; ++r) {
            float bi = bo[ibx + r];
#pragma unroll
            for (int b = 0; b < 4; ++b) {
                int j = j0 + wj + b * 16 + fr;
                D[(size_t)(ibx + r) * N_PIX + j] = acc[a][b][r] * rjv[b] + bi;
            }
        }
    }
}

#undef PV_STAGE
#undef PV_COMP

// ---------------------------------------------------------------------------
// 128x128 K=512 dbuf GEMM machinery (round-5 proven), used by proj2.
// ---------------------------------------------------------------------------

#define PJ_STAGE(ee, tk) do { \
    _Pragma("unroll") \
    for (int ss = 0; ss < 4; ++ss) { \
        gl2lds16(ga + (size_t)ss * 8 * C_DIM + (tk) * 64, \
                 laA + (ee) * (128 * 64) + ss * 8 * 64); \
        gl2lds16(gb + (size_t)ss * 8 * C_DIM + (tk) * 64, \
                 laB + (ee) * (128 * 64) + ss * 8 * 64); \
    } } while (0)

#define PJ_COMP(dd) do { \
    _Pragma("unroll") \
    for (int kk = 0; kk < 2; ++kk) { \
        bf16x8 af[4], bfr[4]; \
        const int ca = ((kk * 4 + fq) ^ sw) << 3; \
        _Pragma("unroll") \
        for (int tt = 0; tt < 4; ++tt) { \
            af[tt]  = *(const bf16x8*)(&As[dd][(wi + tt * 16 + fr) * 64 + ca]); \
            bfr[tt] = *(const bf16x8*)(&Bs[dd][(wj + tt * 16 + fr) * 64 + ca]); \
        } \
        _Pragma("unroll") \
        for (int a = 0; a < 4; ++a) \
        _Pragma("unroll") \
        for (int b = 0; b < 4; ++b) \
            acc[a][b] = __builtin_amdgcn_mfma_f32_16x16x32_bf16( \
                af[a], bfr[b], acc[a][b], 0, 0, 0); \
    } } while (0)

#define PJ_LOOP() do { \
    PJ_STAGE(0, 0); \
    GVM0(); GBAR(); \
    _Pragma("unroll 1") \
    for (int kt = 0; kt < 6; kt += 2) { \
        PJ_STAGE(1, kt + 1); \
        PJ_COMP(0); \
        GVM0(); GBAR(); \
        PJ_STAGE(0, kt + 2); \
        PJ_COMP(1); \
        GVM0(); GBAR(); \
    } \
    PJ_STAGE(1, 7); \
    PJ_COMP(0); \
    GVM0(); GBAR(); \
    PJ_COMP(1); \
    } while (0)

// ---------------------------------------------------------------------------
// proj2: mat0: T = gemm_bt(Xlt, matT)   (no bias, standard [n,c] store)
//        mat1: Vp = gemm_bt(Xgt, Wov)+bov, stored TRANSPOSED [o,m] via LDS.
// Grid 16 x 72 = 1152.
// ---------------------------------------------------------------------------
__global__ __launch_bounds__(256)
void proj2(const __hip_bfloat16* __restrict__ Xlt,
           const __hip_bfloat16* __restrict__ Xgt,
           const __hip_bfloat16* __restrict__ matT,
           const __hip_bfloat16* __restrict__ Wov,
           const float* __restrict__ bovp,
           __hip_bfloat16* __restrict__ Tm,
           __hip_bfloat16* __restrict__ Vp)
{
    __shared__ __hip_bfloat16 As[2][128 * 64];
    __shared__ __hip_bfloat16 Bs[2][128 * 64];

    const int lin = blockIdx.x;
    const int s   = lin % 16;
    const int bz  = s & 7;
    const int m2  = s >> 3;
    const int t2  = lin / 16;
    const int j0  = (t2 & 3) * 128;
    const int i0  = (t2 >> 2) * 128;
    const long sNC = (long)N_PIX * C_DIM;

    const __hip_bfloat16* Ab = (m2 ? Xgt : Xlt) + (size_t)bz * sNC;
    const __hip_bfloat16* Bb = m2 ? Wov : matT;

    const int tid  = threadIdx.x;
    const int lane = tid & 63;
    const int wave = tid >> 6;

    const int lrow = lane >> 3;
    const int lcs  = (lane & 7) ^ lrow;
    const __hip_bfloat16* ga = Ab + (size_t)(i0 + wave * 32 + lrow) * C_DIM + lcs * 8;
    const __hip_bfloat16* gb = Bb + (size_t)(j0 + wave * 32 + lrow) * C_DIM + lcs * 8;
    __hip_bfloat16* laA = &As[0][wave * 32 * 64];
    __hip_bfloat16* laB = &Bs[0][wave * 32 * 64];

    const int fr = lane & 15;
    const int fq = lane >> 4;
    const int sw = fr & 7;
    const int wi = (wave >> 1) * 64;
    const int wj = (wave & 1) * 64;

    f32x4 acc[4][4];
#pragma unroll
    for (int a = 0; a < 4; ++a)
#pragma unroll
        for (int b = 0; b < 4; ++b)
            acc[a][b] = (f32x4){0.f, 0.f, 0.f, 0.f};

    PJ_LOOP();

    const int orow = fq * 4;
    if (m2 == 0) {
        __hip_bfloat16* D = Tm + (size_t)bz * sNC;
#pragma unroll
        for (int a = 0; a < 4; ++a) {
            int ibx = i0 + wi + a * 16 + orow;
#pragma unroll
            for (int b = 0; b < 4; ++b) {
                int j = j0 + wj + b * 16 + fr;
#pragma unroll
                for (int r = 0; r < 4; ++r)
                    D[(size_t)(ibx + r) * C_DIM + j] = __float2bfloat16(acc[a][b][r]);
            }
        }
    } else {
        // transposed store: Vp[(j0+jj)*N_PIX + (i0+ii)] via padded-LDS transpose
        __hip_bfloat16* Dvp = Vp + (size_t)bz * sNC;
        float bvb[4];
#pragma unroll
        for (int b = 0; b < 4; ++b)
            bvb[b] = bovp[j0 + wj + b * 16 + fr];
        __syncthreads();
        __hip_bfloat16* Tt = (__hip_bfloat16*)&As[0][0];   // [128][65] bf16
#pragma unroll
        for (int h = 0; h < 2; ++h) {
            if ((wave & 1) == h) {
#pragma unroll
                for (int a = 0; a < 4; ++a) {
                    int rl = wi + a * 16 + orow;
#pragma unroll
                    for (int b = 0; b < 4; ++b) {
                        int cl = b * 16 + fr;
#pragma unroll
                        for (int r = 0; r < 4; ++r)
                            Tt[(rl + r) * 65 + cl] =
                                __float2bfloat16(acc[a][b][r] + bvb[b]);
                    }
                }
            }
            __syncthreads();
            {
                const int lj = tid >> 2, ic = (tid & 3) * 32;
                union { __hip_bfloat16 h8[32]; int4 v4[4]; } u;
#pragma unroll
                for (int q = 0; q < 32; ++q)
                    u.h8[q] = Tt[(ic + q) * 65 + lj];
                __hip_bfloat16* dst = Dvp + (size_t)(j0 + h * 64 + lj) * N_PIX + i0 + ic;
#pragma unroll
                for (int q4 = 0; q4 < 4; ++q4)
                    ((int4*)dst)[q4] = u.v4[q4];
            }
            __syncthreads();
        }
    }
}

#undef PJ_STAGE
#undef PJ_COMP
#undef PJ_LOOP

// ---------------------------------------------------------------------------
// prep (grid 4713):
//   [0,16)     matT tiles: matT[c2][c1]=sum_o Wk[o,c2]Wq[o,c1]  (fp32-direct)
//   [16,32)    Wov tiles:  Wov[o][c]  =sum_o2 Wo[o,o2]Wv[o2,c]  (fp32-direct)
//   [32,104)   v-blocks:   v[b,m]=sum_c glox[b,c,m]·wv[c], wv recomputed
//   [104]      bov[o] = Wo[o,:]·bv
//   [105,4713) input transpose+cast (z<8 locx->Xlt else glox->Xgt)
// All front blocks read only fp32 inputs -> order-independent, overlapped.
// Shared mem: single 16640B arena (same as transpose blocks -> no occ change).
// ---------------------------------------------------------------------------
__global__ __launch_bounds__(256)
void prep(const float* __restrict__ locx, const float* __restrict__ glox,
          const float* __restrict__ Wq, const float* __restrict__ Wk,
          const float* __restrict__ Wv, const float* __restrict__ Wo,
          const float* __restrict__ bq, const float* __restrict__ bv,
          __hip_bfloat16* __restrict__ Xlt, __hip_bfloat16* __restrict__ Xgt,
          __hip_bfloat16* __restrict__ matT, __hip_bfloat16* __restrict__ Wov,
          float* __restrict__ vvec, float* __restrict__ bovbuf)
{
    __shared__ __align__(16) char shm[16640];
    const int lin = blockIdx.x;
    const int tid = threadIdx.x;

    if (lin < 32) {
        // 128x128 tile GEMM, K=512, BK=32, single-buffered, bf16 staged on the fly
        __hip_bfloat16* As = (__hip_bfloat16*)shm;            // [128][32]
        __hip_bfloat16* Bs = (__hip_bfloat16*)(shm + 8192);   // [128][32]
        const int m2 = lin >> 4;
        const int t2 = lin & 15;
        const int j0 = (t2 & 3) * 128;
        const int i0 = (t2 >> 2) * 128;

        const int lane = tid & 63;
        const int wave = tid >> 6;
        const int fr = lane & 15;
        const int fq = lane >> 4;
        const int sw2 = fr & 3;
        const int wi = (wave >> 1) * 64;
        const int wj = (wave & 1) * 64;

        f32x4 acc[4][4];
#pragma unroll
        for (int a = 0; a < 4; ++a)
#pragma unroll
            for (int b = 0; b < 4; ++b)
                acc[a][b] = (f32x4){0.f, 0.f, 0.f, 0.f};

        const float* SB = m2 ? Wv : Wq;   // B operand, transposed staging
        // transposed-staging thread mapping
        const int o_r = tid >> 3;          // 0..31 (o within chunk)
        const int cc0 = (tid & 7) * 16;    // col base

#pragma unroll 1
        for (int o0 = 0; o0 < 512; o0 += 32) {
            // ---- stage A ----
            if (m2 == 0) {
                // As[c][o] = Wk[o0+o][i0+c]  (transposed, swizzled scalar stores)
                const float* src = Wk + (size_t)(o0 + o_r) * 512 + i0 + cc0;
                float v[16];
#pragma unroll
                for (int q4 = 0; q4 < 4; ++q4) {
                    float4 f = *(const float4*)(src + q4 * 4);
                    v[q4 * 4 + 0] = f.x; v[q4 * 4 + 1] = f.y;
                    v[q4 * 4 + 2] = f.z; v[q4 * 4 + 3] = f.w;
                }
#pragma unroll
                for (int q = 0; q < 16; ++q) {
                    const int col = cc0 + q;
                    const int byt = col * 64 + ((((o_r >> 3) ^ (col & 3)) << 4))
                                  + (o_r & 7) * 2;
                    *(__hip_bfloat16*)((char*)As + byt) = __float2bfloat16(v[q]);
                }
            } else {
                // As[r][o2] = Wo[i0+r][o0+o2]  (direct, vectorized swizzled)
                const int r = tid >> 1;
#pragma unroll
                for (int s = 0; s < 2; ++s) {
                    const int cp = (tid & 1) * 2 + s;   // chunk 0..3
                    const float* src = Wo + (size_t)(i0 + r) * 512 + o0 + cp * 8;
                    float4 f0 = *(const float4*)(src);
                    float4 f1 = *(const float4*)(src + 4);
                    union { __hip_bfloat16 h[8]; int4 v4; } u;
                    u.h[0] = __float2bfloat16(f0.x); u.h[1] = __float2bfloat16(f0.y);
                    u.h[2] = __float2bfloat16(f0.z); u.h[3] = __float2bfloat16(f0.w);
                    u.h[4] = __float2bfloat16(f1.x); u.h[5] = __float2bfloat16(f1.y);
                    u.h[6] = __float2bfloat16(f1.z); u.h[7] = __float2bfloat16(f1.w);
                    *(int4*)(As + r * 32 + ((cp ^ (r & 3)) << 3)) = u.v4;
                }
            }
            // ---- stage B (transposed): Bs[c][o] = SB[o0+o][j0+c] ----
            {
                const float* src = SB + (size_t)(o0 + o_r) * 512 + j0 + cc0;
                float v[16];
#pragma unroll
                for (int q4 = 0; q4 < 4; ++q4) {
                    float4 f = *(const float4*)(src + q4 * 4);
                    v[q4 * 4 + 0] = f.x; v[q4 * 4 + 1] = f.y;
                    v[q4 * 4 + 2] = f.z; v[q4 * 4 + 3] = f.w;
                }
#pragma unroll
                for (int q = 0; q < 16; ++q) {
                    const int col = cc0 + q;
                    const int byt = col * 64 + ((((o_r >> 3) ^ (col & 3)) << 4))
                                  + (o_r & 7) * 2;
                    *(__hip_bfloat16*)((char*)Bs + byt) = __float2bfloat16(v[q]);
                }
            }
            __syncthreads();
            // ---- MFMA (K=32) ----
            bf16x8 af[4], bfm[4];
#pragma unroll
            for (int tt = 0; tt < 4; ++tt) {
                af[tt]  = *(const bf16x8*)(As + (wi + tt * 16 + fr) * 32
                                              + ((fq ^ sw2) << 3));
                bfm[tt] = *(const bf16x8*)(Bs + (wj + tt * 16 + fr) * 32
                                              + ((fq ^ sw2) << 3));
            }
#pragma unroll
            for (int a = 0; a < 4; ++a)
#pragma unroll
                for (int b = 0; b < 4; ++b)
                    acc[a][b] = __builtin_amdgcn_mfma_f32_16x16x32_bf16(
                        af[a], bfm[b], acc[a][b], 0, 0, 0);
            __syncthreads();
        }
        __hip_bfloat16* D = m2 ? Wov : matT;
        const int orow = fq * 4;
#pragma unroll
        for (int a = 0; a < 4; ++a) {
            int ibx = i0 + wi + a * 16 + orow;
#pragma unroll
            for (int b = 0; b < 4; ++b) {
                int j = j0 + wj + b * 16 + fr;
#pragma unroll
                for (int r = 0; r < 4; ++r)
                    D[(size_t)(ibx + r) * 512 + j] = __float2bfloat16(acc[a][b][r]);
            }
        }
    } else if (lin < 104) {
        // v-block: wv recompute (Wk L2-resident) + glox column dot (fp32)
        const int blk = lin - 32;
        const int b   = blk / 9;
        const int m0  = (blk % 9) * 256;
        float a0 = 0.f, a1 = 0.f;
        for (int o = 0; o < 512; ++o) {
            const float bb = bq[o];
            a0 += Wk[(size_t)o * 512 + tid] * bb;
            a1 += Wk[(size_t)o * 512 + tid + 256] * bb;
        }
        float* wvs = (float*)shm;
        wvs[tid] = a0;
        wvs[tid + 256] = a1;
        __syncthreads();
        const float* col = glox + (size_t)b * 512 * N_PIX + m0 + tid;
        float acc = 0.f;
        for (int c = 0; c < 512; ++c)
            acc += col[(size_t)c * N_PIX] * wvs[c];
        vvec[(size_t)b * N_PIX + m0 + tid] = acc;
    } else if (lin == 104) {
        // bov[o] = Wo[o,:]·bv
#pragma unroll
        for (int half = 0; half < 2; ++half) {
            int o = tid + half * 256;
            float acc = 0.f;
            for (int c4 = 0; c4 < 128; ++c4) {
                float4 f = *(const float4*)(Wo + (size_t)o * 512 + c4 * 4);
                float4 g = *(const float4*)(bv + c4 * 4);
                acc += f.x * g.x + f.y * g.y + f.z * g.z + f.w * g.w;
            }
            bovbuf[o] = acc;
        }
    } else {
        // input transpose+cast
        float* t = (float*)shm;                    // [64][65]
        const int lin2 = lin - 105;
        const int z  = lin2 & 15;
        const int t2 = lin2 >> 4;
        const int c0 = (t2 & 7) * 64;
        const int n0 = (t2 >> 3) * 64;
        const size_t b = z & 7;
        const float* Xb = ((z < 8) ? locx : glox) + b * (size_t)C_DIM * N_PIX;
        __hip_bfloat16* Xt = (z < 8) ? Xlt : Xgt;

        const int n_l = tid & 63;
        const int c_b = tid >> 6;
#pragma unroll
        for (int s = 0; s < 16; ++s) {
            int c_l = c_b + s * 4;
            t[c_l * 65 + n_l] = Xb[(size_t)(c0 + c_l) * N_PIX + n0 + n_l];
        }
        __syncthreads();

        const int cc = (tid & 7) * 8;
        const int nb = tid >> 3;
#pragma unroll
        for (int it = 0; it < 2; ++it) {
            int n2 = nb + it * 32;
            union { __hip_bfloat16 h[8]; int4 v; } u;
#pragma unroll
            for (int w = 0; w < 8; ++w)
                u.h[w] = __float2bfloat16(t[(cc + w) * 65 + n2]);
            *(int4*)(&Xt[(b * N_PIX + n0 + n2) * C_DIM + c0 + cc]) = u.v;
        }
    }
}

// ---------------------------------------------------------------------------
extern "C" void kernel_launch(void* const* d_in, const int* in_sizes, int n_in,
                              void* d_out, int out_size, void* d_ws, size_t ws_size,
                              hipStream_t stream)
{
    const float* locx = (const float*)d_in[0];
    const float* glox = (const float*)d_in[1];
    const float* Wq = (const float*)d_in[2];
    const float* bq = (const float*)d_in[3];
    const float* Wk = (const float*)d_in[4];
    const float* bk = (const float*)d_in[5];   // unused: u[n],c0 cancel in softmax
    const float* Wv = (const float*)d_in[6];
    const float* bv = (const float*)d_in[7];
    const float* Wo = (const float*)d_in[8];
    const float* bo = (const float*)d_in[9];
    float* out = (float*)d_out;
    (void)bk;

    const int C = C_DIM, N = N_PIX;
    const size_t WB   = (size_t)C * C * 2;             // 0.5 MB bf16 mat
    const size_t szX  = (size_t)N_BATCH * N * C * 2;   // 18.87 MB
    const size_t szP1 = (size_t)N * N * 2;
    const size_t szRP = (size_t)NJB * N_BATCH * N * 4;
    const size_t szV  = (size_t)N_BATCH * N * 4;       // vvec

    char* ws = (char*)d_ws;
    size_t off = 0;
    auto alloc = [&](size_t bytes) {
        char* p = ws + off;
        off += (bytes + 255) & ~(size_t)255;
        return p;
    };
    __hip_bfloat16* matT  = (__hip_bfloat16*)alloc(WB);
    __hip_bfloat16* Wov   = (__hip_bfloat16*)alloc(WB);
    float*          bovb  = (float*)alloc(512 * 4);
    float*          vvec  = (float*)alloc(szV);
    __hip_bfloat16* Xlt   = (__hip_bfloat16*)alloc(szX);
    __hip_bfloat16* Xgt   = (__hip_bfloat16*)alloc(szX);
    __hip_bfloat16* Tm    = (__hip_bfloat16*)alloc(szX);
    __hip_bfloat16* Vp    = (__hip_bfloat16*)alloc(szX);
    float*          rp    = (float*)alloc(szRP);
    const size_t fixed = off;
    bool full = (ws_size >= fixed + 8 * szP1 + 4096);
    __hip_bfloat16* Pu = (__hip_bfloat16*)alloc(full ? 8 * szP1 : szP1);

    const dim3 blk(256);

    prep<<<dim3(4713), blk, 0, stream>>>(locx, glox, Wq, Wk, Wv, Wo, bq, bv,
                                         Xlt, Xgt, matT, Wov, vvec, bovb);
    proj2<<<dim3(16 * 72), blk, 0, stream>>>(Xlt, Xgt, matT, Wov, bovb, Tm, Vp);

    if (full) {
        s_only<8><<<dim3(8 * 81), dim3(512), 0, stream>>>(
            Tm, Xgt, Pu, rp, vvec, 0, (long)N * N);
        pv_out<8><<<dim3(8 * 72), blk, 0, stream>>>(
            Vp, Pu, out, bo, rp, 0, (long)N * N);
    } else {
        for (int r = 0; r < N_BATCH; ++r) {
            s_only<1><<<dim3(81), dim3(512), 0, stream>>>(
                Tm, Xgt, Pu, rp, vvec, r, 0);
            pv_out<1><<<dim3(72), blk, 0, stream>>>(
                Vp, Pu, out, bo, rp, r, 0);
        }
    }
}

// Round 8
// 350.408 us; speedup vs baseline: 1.0450x; 1.0450x over previous
//
#include <hip/hip_runtime.h>
#include <hip/hip_bf16.h>

typedef __attribute__((ext_vector_type(4))) float f32x4;
typedef __attribute__((ext_vector_type(8))) short bf16x8;
typedef __attribute__((ext_vector_type(4))) short s16x4;

#define C_DIM 512
#define N_PIX 2304
#define N_BATCH 8
#define ATT_SCALE 0.04419417382415922f
#define NJB 9                       // N_PIX / 256 (s-kernel j-tiles)

typedef __attribute__((address_space(3))) unsigned int lds_u32;
typedef const __attribute__((address_space(1))) unsigned int glob_u32;

__device__ __forceinline__ void gl2lds16(const __hip_bfloat16* g, __hip_bfloat16* l)
{
    __builtin_amdgcn_global_load_lds((glob_u32*)g, (lds_u32*)l, 16, 0, 0);
}

#define GBAR() __builtin_amdgcn_s_barrier()
#define GVM0() asm volatile("s_waitcnt vmcnt(0)" ::: "memory")
#define GVM8() asm volatile("s_waitcnt vmcnt(8)" ::: "memory")

// ===========================================================================
// ALGEBRAIC FOLDS (round-6/7, kept):
//  scores/sc = Xl·(Wq^T Wk)·Xg^T + v[m]  (row-constant terms cancel in softmax)
//  Vp = (Wo·Wv)·Xg^T + bov
// ROUND-8: pv_out/proj2 K-loops converted from vmcnt(0)-drain-per-tile to
// 2-tile-deep COUNTED pipeline (vmcnt(8)): each STAGE = 8 gl2lds/wave;
// prologue stages tiles 0,1; iter kt waits oldest 8 (tile kt), computes,
// barriers, stages kt+2. Latency hidden within the block regardless of
// occupancy (fixes round-7's 1-block/CU latency exposure, pv_out 98us).
// ===========================================================================

// ---------------------------------------------------------------------------
// s_only: 256x256 8-phase (round-1-proven structure), S-tiles only (648 blks).
// Pu[n,m] = exp(SC*(sum_c T[n,c]Xgt[m,c] + v[m])), rp row-sum partials.
// ---------------------------------------------------------------------------

#define BAR()  __builtin_amdgcn_s_barrier()
#define LGK0() asm volatile("s_waitcnt lgkmcnt(0)" ::: "memory")
#define VM4()  asm volatile("s_waitcnt vmcnt(4)" ::: "memory")
#define VM0()  asm volatile("s_waitcnt vmcnt(0)" ::: "memory")
#define PRIO(p) __builtin_amdgcn_s_setprio(p)

#define STAGE_A(dd, hh, tk) do { \
    _Pragma("unroll") \
    for (int ss = 0; ss < 2; ++ss) { \
        const int ur0 = wave * 16 + ss * 8; \
        const int row0 = ((ur0 >> 6) << 7) + (hh) * 64 + (ur0 & 63); \
        gl2lds16(gA + (size_t)row0 * C_DIM + (tk) * 64, \
                 (__hip_bfloat16*)&LA[dd][row0 * 64]); \
    } } while (0)

#define STAGE_B(dd, bb, tk) do { \
    _Pragma("unroll") \
    for (int ss = 0; ss < 2; ++ss) { \
        const int ur0 = wave * 16 + ss * 8; \
        const int row0 = ((ur0 >> 5) << 6) + (bb) * 32 + (ur0 & 31); \
        gl2lds16(gB + (size_t)row0 * C_DIM + (tk) * 64, \
                 (__hip_bfloat16*)&LB[dd][row0 * 64]); \
    } } while (0)

#define LOAD_A(dd, hh) do { \
    _Pragma("unroll") \
    for (int tt = 0; tt < 4; ++tt) { \
        const int rb = (wr * 128 + (hh) * 64 + tt * 16 + fr) * 64; \
        _Pragma("unroll") \
        for (int kk = 0; kk < 2; ++kk) \
            aF[tt][kk] = *(const bf16x8*)(&LA[dd][rb + (((kk * 4 + fq) ^ sw) << 3)]); \
    } } while (0)

#define LOAD_B(dd, bb, dst) do { \
    _Pragma("unroll") \
    for (int s2 = 0; s2 < 2; ++s2) { \
        const int rb = (wc * 64 + (bb) * 32 + s2 * 16 + fr) * 64; \
        _Pragma("unroll") \
        for (int kk = 0; kk < 2; ++kk) \
            dst[s2][kk] = *(const bf16x8*)(&LB[dd][rb + (((kk * 4 + fq) ^ sw) << 3)]); \
    } } while (0)

#define MFMA_Q(HH, BB, bsrc) do { \
    _Pragma("unroll") \
    for (int tt = 0; tt < 4; ++tt) \
    _Pragma("unroll") \
    for (int s2 = 0; s2 < 2; ++s2) \
    _Pragma("unroll") \
    for (int kk = 0; kk < 2; ++kk) \
        acc[(HH) * 4 + tt][(BB) * 2 + s2] = __builtin_amdgcn_mfma_f32_16x16x32_bf16( \
            aF[tt][kk], bsrc[s2][kk], acc[(HH) * 4 + tt][(BB) * 2 + s2], 0, 0, 0); \
    } while (0)

template<int NS>
__global__ __launch_bounds__(512, 2)
void s_only(const __hip_bfloat16* __restrict__ Tm, const __hip_bfloat16* __restrict__ Xgt,
            __hip_bfloat16* __restrict__ Pu, float* __restrict__ rp,
            const float* __restrict__ vvec, int bz_off, long sPu)
{
    __shared__ __hip_bfloat16 LA[2][256 * 64];
    __shared__ __hip_bfloat16 LB[2][256 * 64];

    const int lin = blockIdx.x;
    const int bz  = lin % NS + bz_off;
    const int t   = lin / NS;
    const int ib  = t / 9;
    const int jb  = t % 9;
    const long sQ = (long)N_PIX * C_DIM;

    const __hip_bfloat16* A = Tm  + (size_t)bz * sQ;
    const __hip_bfloat16* B = Xgt + (size_t)bz * sQ;
    __hip_bfloat16* D = Pu + (size_t)bz * (size_t)sPu;

    const int i0 = ib * 256;
    const int j0 = jb * 256;

    const int tid  = threadIdx.x;
    const int lane = tid & 63;
    const int wave = tid >> 6;

    const int lrow = lane >> 3;
    const int lcs  = (lane & 7) ^ lrow;           // XOR chunk swizzle (store side)
    const __hip_bfloat16* gA = A + (size_t)(i0 + lrow) * C_DIM + lcs * 8;
    const __hip_bfloat16* gB = B + (size_t)(j0 + lrow) * C_DIM + lcs * 8;

    const int fr = lane & 15;
    const int fq = lane >> 4;
    const int sw = fr & 7;                        // row&7 on read side
    const int wr = wave >> 2;                     // 0..1 (row wave)
    const int wc = wave & 3;                      // 0..3 (col wave)

    f32x4 acc[8][4];
#pragma unroll
    for (int a = 0; a < 8; ++a)
#pragma unroll
        for (int b = 0; b < 4; ++b)
            acc[a][b] = (f32x4){0.f, 0.f, 0.f, 0.f};

    bf16x8 aF[4][2], bF0[2][2], bF1[2][2];

    // prologue: tile0 (4 halves) + tile1 {A0,B1}; vmcnt(4) -> tile0 landed
    STAGE_A(0, 0, 0); STAGE_B(0, 0, 0); STAGE_B(0, 1, 0); STAGE_A(0, 1, 0);
    STAGE_A(1, 0, 1); STAGE_B(1, 1, 1);
    VM4();
    BAR();

    for (int kt = 0; kt < 6; ++kt) {
        const int d = kt & 1, e = d ^ 1;
        LOAD_A(d, 0); LOAD_B(d, 0, bF0);
        STAGE_A(e, 1, kt + 1);
        BAR(); LGK0();
        PRIO(1); MFMA_Q(0, 0, bF0); PRIO(0);
        BAR();
        LOAD_B(d, 1, bF1);
        STAGE_B(e, 0, kt + 1);
        BAR(); LGK0();
        PRIO(1); MFMA_Q(0, 1, bF1); PRIO(0);
        BAR();
        LOAD_A(d, 1);
        STAGE_A(d, 0, kt + 2);
        BAR(); LGK0();
        PRIO(1); MFMA_Q(1, 1, bF1); PRIO(0);
        BAR();
        STAGE_B(d, 1, kt + 2);
        VM4();
        BAR();
        PRIO(1); MFMA_Q(1, 0, bF0); PRIO(0);
        BAR();
    }
    {   // K-tile 6 (buf 0): stage only tile-7 {A1,B0}
        LOAD_A(0, 0); LOAD_B(0, 0, bF0);
        STAGE_A(1, 1, 7);
        BAR(); LGK0();
        PRIO(1); MFMA_Q(0, 0, bF0); PRIO(0);
        BAR();
        LOAD_B(0, 1, bF1);
        STAGE_B(1, 0, 7);
        BAR(); LGK0();
        PRIO(1); MFMA_Q(0, 1, bF1); PRIO(0);
        BAR();
        LOAD_A(0, 1);
        BAR(); LGK0();
        PRIO(1); MFMA_Q(1, 1, bF1); PRIO(0);
        BAR();
        VM0();
        BAR();
        PRIO(1); MFMA_Q(1, 0, bF0); PRIO(0);
        BAR();
    }
    {   // K-tile 7 (buf 1): no staging
        LOAD_A(1, 0); LOAD_B(1, 0, bF0);
        BAR(); LGK0();
        PRIO(1); MFMA_Q(0, 0, bF0); PRIO(0);
        BAR();
        LOAD_B(1, 1, bF1);
        BAR(); LGK0();
        PRIO(1); MFMA_Q(0, 1, bF1); PRIO(0);
        BAR();
        LOAD_A(1, 1);
        BAR(); LGK0();
        PRIO(1); MFMA_Q(1, 1, bF1); PRIO(0);
        BAR();
        PRIO(1); MFMA_Q(1, 0, bF0); PRIO(0);
    }

    // epilogue: exp(SC*(acc + v[m])), rp partials
    float vb[4];
#pragma unroll
    for (int b = 0; b < 4; ++b)
        vb[b] = vvec[(size_t)bz * N_PIX + j0 + wc * 64 + b * 16 + fr];

    float rpart[8][4];
#pragma unroll
    for (int a = 0; a < 8; ++a)
#pragma unroll
        for (int r = 0; r < 4; ++r)
            rpart[a][r] = 0.f;
#pragma unroll
    for (int a = 0; a < 8; ++a) {
        const int grow = i0 + wr * 128 + a * 16 + fq * 4;
#pragma unroll
        for (int b = 0; b < 4; ++b) {
            const int col = j0 + wc * 64 + b * 16 + fr;
#pragma unroll
            for (int r = 0; r < 4; ++r) {
                float v = __expf(ATT_SCALE * (acc[a][b][r] + vb[b]));
                rpart[a][r] += v;
                D[(size_t)(grow + r) * N_PIX + col] = __float2bfloat16(v);
            }
        }
    }
#pragma unroll
    for (int m = 1; m < 16; m <<= 1)
#pragma unroll
        for (int a = 0; a < 8; ++a)
#pragma unroll
            for (int r = 0; r < 4; ++r)
                rpart[a][r] += __shfl_xor(rpart[a][r], m);
    float* rsl = (float*)&LA[0][0];
    __syncthreads();
    if (fr == 0) {
#pragma unroll
        for (int a = 0; a < 8; ++a)
#pragma unroll
            for (int r = 0; r < 4; ++r)
                rsl[wave * 128 + a * 16 + fq * 4 + r] = rpart[a][r];
    }
    __syncthreads();
    if (tid < 256) {
        const int wr2 = tid >> 7, rl = tid & 127;
        float s = rsl[(wr2 * 4 + 0) * 128 + rl] + rsl[(wr2 * 4 + 1) * 128 + rl]
                + rsl[(wr2 * 4 + 2) * 128 + rl] + rsl[(wr2 * 4 + 3) * 128 + rl];
        rp[((size_t)jb * N_BATCH + bz) * N_PIX + i0 + tid] = s;
    }
}

#undef STAGE_A
#undef STAGE_B
#undef LOAD_A
#undef LOAD_B
#undef MFMA_Q
#undef BAR
#undef LGK0
#undef VM4
#undef VM0
#undef PRIO

// ---------------------------------------------------------------------------
// PV + output, ROUND-8: 128x128 tile, 36 K-tiles, 2-tile-deep counted pipeline.
// Per STAGE: 8 gl2lds/wave (4A+4B). vmcnt(8) = oldest tile landed, next in
// flight. out[o,n] = rinv[n]*sum_m Vp[o,m]Pu[n,m] + bo[o]. Grid NS*72 i-fast.
// ---------------------------------------------------------------------------

#define PV_STAGE(ee, tk) do { \
    _Pragma("unroll") \
    for (int ss = 0; ss < 4; ++ss) { \
        gl2lds16(ga + (size_t)ss * 8 * N_PIX + (tk) * 64, \
                 laA + (ee) * (128 * 64) + ss * 8 * 64); \
        gl2lds16(gb + (size_t)ss * 8 * N_PIX + (tk) * 64, \
                 laB + (ee) * (128 * 64) + ss * 8 * 64); \
    } } while (0)

#define PV_COMP(dd) do { \
    _Pragma("unroll") \
    for (int kk = 0; kk < 2; ++kk) { \
        bf16x8 af[4], bfr[4]; \
        const int ca = ((kk * 4 + fq) ^ sw) << 3; \
        _Pragma("unroll") \
        for (int tt = 0; tt < 4; ++tt) { \
            af[tt]  = *(const bf16x8*)(&As[dd][(wi + tt * 16 + fr) * 64 + ca]); \
            bfr[tt] = *(const bf16x8*)(&Bs[dd][(wj + tt * 16 + fr) * 64 + ca]); \
        } \
        _Pragma("unroll") \
        for (int a = 0; a < 4; ++a) \
        _Pragma("unroll") \
        for (int b = 0; b < 4; ++b) \
            acc[a][b] = __builtin_amdgcn_mfma_f32_16x16x32_bf16( \
                af[a], bfr[b], acc[a][b], 0, 0, 0); \
    } } while (0)

template<int NS>
__global__ __launch_bounds__(256)
void pv_out(const __hip_bfloat16* __restrict__ Vp, const __hip_bfloat16* __restrict__ Pu,
            float* __restrict__ out, const float* __restrict__ bo,
            const float* __restrict__ rp, int bz_off, long sPu)
{
    __shared__ __hip_bfloat16 As[2][128 * 64];
    __shared__ __hip_bfloat16 Bs[2][128 * 64];

    const int lin = blockIdx.x;
    const int bz  = lin % NS + bz_off;
    const int t   = lin / NS;
    const int ib  = t % 4;       // i-fast: consecutive blocks share Pu j-tile
    const int jb  = t / 4;
    const int i0  = ib * 128;
    const int j0  = jb * 128;

    const long sCN = (long)C_DIM * N_PIX;
    const __hip_bfloat16* A = Vp + (size_t)bz * sCN;         // [C,N] lda=N
    const __hip_bfloat16* B = Pu + (size_t)bz * (size_t)sPu; // [N,N] ldb=N
    float* D = out + (size_t)bz * sCN;

    const int tid  = threadIdx.x;
    const int lane = tid & 63;
    const int wave = tid >> 6;

    const int lrow = lane >> 3;
    const int lcs  = (lane & 7) ^ lrow;
    const __hip_bfloat16* ga = A + (size_t)(i0 + wave * 32 + lrow) * N_PIX + lcs * 8;
    const __hip_bfloat16* gb = B + (size_t)(j0 + wave * 32 + lrow) * N_PIX + lcs * 8;
    __hip_bfloat16* laA = &As[0][wave * 32 * 64];
    __hip_bfloat16* laB = &Bs[0][wave * 32 * 64];

    const int fr = lane & 15;
    const int fq = lane >> 4;
    const int sw = fr & 7;
    const int wi = (wave >> 1) * 64;
    const int wj = (wave & 1) * 64;

    f32x4 acc[4][4];
#pragma unroll
    for (int a = 0; a < 4; ++a)
#pragma unroll
        for (int b = 0; b < 4; ++b)
            acc[a][b] = (f32x4){0.f, 0.f, 0.f, 0.f};

    // prologue: 2 tiles in flight
    PV_STAGE(0, 0);
    PV_STAGE(1, 1);

    // main: tiles 0..33, stage kt+2 at bottom (2 compute-phases of cover)
#pragma unroll 1
    for (int kt = 0; kt < 34; kt += 2) {
        GVM8();                 // tile kt landed; kt+1's 8 loads in flight
        GBAR();
        PV_COMP(0);
        GBAR();                 // all waves done reading buf0
        PV_STAGE(0, kt + 2);
        GVM8();                 // tile kt+1 landed; kt+2 in flight
        GBAR();
        PV_COMP(1);
        GBAR();
        PV_STAGE(1, kt + 3);
    }
    // tail: tiles 34 (buf0), 35 (buf1); no more staging
    GVM8();
    GBAR();
    PV_COMP(0);
    GVM0();                     // tile 35 landed
    GBAR();
    PV_COMP(1);

    const int orow = fq * 4;
    float rjv[4];
#pragma unroll
    for (int b = 0; b < 4; ++b) {
        int j = j0 + wj + b * 16 + fr;
        float s = 0.f;
#pragma unroll
        for (int jj = 0; jj < NJB; ++jj)
            s += rp[((size_t)jj * N_BATCH + bz) * N_PIX + j];
        rjv[b] = 1.f / s;
    }

#pragma unroll
    for (int a = 0; a < 4; ++a) {
        int ibx = i0 + wi + a * 16 + orow;
#pragma unroll
        for (int r = 0; r < 4; ++r) {
            float bi = bo[ibx + r];
#pragma unroll
            for (int b = 0; b < 4; ++b) {
                int j = j0 + wj + b * 16 + fr;
                D[(size_t)(ibx + r) * N_PIX + j] = acc[a][b][r] * rjv[b] + bi;
            }
        }
    }
}

#undef PV_STAGE
#undef PV_COMP

// ---------------------------------------------------------------------------
// 128x128 K=512 GEMM machinery, ROUND-8: same 2-deep counted pipeline.
// ---------------------------------------------------------------------------

#define PJ_STAGE(ee, tk) do { \
    _Pragma("unroll") \
    for (int ss = 0; ss < 4; ++ss) { \
        gl2lds16(ga + (size_t)ss * 8 * C_DIM + (tk) * 64, \
                 laA + (ee) * (128 * 64) + ss * 8 * 64); \
        gl2lds16(gb + (size_t)ss * 8 * C_DIM + (tk) * 64, \
                 laB + (ee) * (128 * 64) + ss * 8 * 64); \
    } } while (0)

#define PJ_COMP(dd) do { \
    _Pragma("unroll") \
    for (int kk = 0; kk < 2; ++kk) { \
        bf16x8 af[4], bfr[4]; \
        const int ca = ((kk * 4 + fq) ^ sw) << 3; \
        _Pragma("unroll") \
        for (int tt = 0; tt < 4; ++tt) { \
            af[tt]  = *(const bf16x8*)(&As[dd][(wi + tt * 16 + fr) * 64 + ca]); \
            bfr[tt] = *(const bf16x8*)(&Bs[dd][(wj + tt * 16 + fr) * 64 + ca]); \
        } \
        _Pragma("unroll") \
        for (int a = 0; a < 4; ++a) \
        _Pragma("unroll") \
        for (int b = 0; b < 4; ++b) \
            acc[a][b] = __builtin_amdgcn_mfma_f32_16x16x32_bf16( \
                af[a], bfr[b], acc[a][b], 0, 0, 0); \
    } } while (0)

#define PJ_LOOP() do { \
    PJ_STAGE(0, 0); \
    PJ_STAGE(1, 1); \
    _Pragma("unroll 1") \
    for (int kt = 0; kt < 6; kt += 2) { \
        GVM8(); GBAR(); \
        PJ_COMP(0); \
        GBAR(); \
        PJ_STAGE(0, kt + 2); \
        GVM8(); GBAR(); \
        PJ_COMP(1); \
        GBAR(); \
        PJ_STAGE(1, kt + 3); \
    } \
    GVM8(); GBAR(); \
    PJ_COMP(0); \
    GVM0(); GBAR(); \
    PJ_COMP(1); \
    } while (0)

// ---------------------------------------------------------------------------
// proj2: mat0: T = gemm_bt(Xlt, matT)   (no bias, standard [n,c] store)
//        mat1: Vp = gemm_bt(Xgt, Wov)+bov, stored TRANSPOSED [o,m] via LDS.
// Grid 16 x 72 = 1152.
// ---------------------------------------------------------------------------
__global__ __launch_bounds__(256)
void proj2(const __hip_bfloat16* __restrict__ Xlt,
           const __hip_bfloat16* __restrict__ Xgt,
           const __hip_bfloat16* __restrict__ matT,
           const __hip_bfloat16* __restrict__ Wov,
           const float* __restrict__ bovp,
           __hip_bfloat16* __restrict__ Tm,
           __hip_bfloat16* __restrict__ Vp)
{
    __shared__ __hip_bfloat16 As[2][128 * 64];
    __shared__ __hip_bfloat16 Bs[2][128 * 64];

    const int lin = blockIdx.x;
    const int s   = lin % 16;
    const int bz  = s & 7;
    const int m2  = s >> 3;
    const int t2  = lin / 16;
    const int j0  = (t2 & 3) * 128;
    const int i0  = (t2 >> 2) * 128;
    const long sNC = (long)N_PIX * C_DIM;

    const __hip_bfloat16* Ab = (m2 ? Xgt : Xlt) + (size_t)bz * sNC;
    const __hip_bfloat16* Bb = m2 ? Wov : matT;

    const int tid  = threadIdx.x;
    const int lane = tid & 63;
    const int wave = tid >> 6;

    const int lrow = lane >> 3;
    const int lcs  = (lane & 7) ^ lrow;
    const __hip_bfloat16* ga = Ab + (size_t)(i0 + wave * 32 + lrow) * C_DIM + lcs * 8;
    const __hip_bfloat16* gb = Bb + (size_t)(j0 + wave * 32 + lrow) * C_DIM + lcs * 8;
    __hip_bfloat16* laA = &As[0][wave * 32 * 64];
    __hip_bfloat16* laB = &Bs[0][wave * 32 * 64];

    const int fr = lane & 15;
    const int fq = lane >> 4;
    const int sw = fr & 7;
    const int wi = (wave >> 1) * 64;
    const int wj = (wave & 1) * 64;

    f32x4 acc[4][4];
#pragma unroll
    for (int a = 0; a < 4; ++a)
#pragma unroll
        for (int b = 0; b < 4; ++b)
            acc[a][b] = (f32x4){0.f, 0.f, 0.f, 0.f};

    PJ_LOOP();

    const int orow = fq * 4;
    if (m2 == 0) {
        __hip_bfloat16* D = Tm + (size_t)bz * sNC;
#pragma unroll
        for (int a = 0; a < 4; ++a) {
            int ibx = i0 + wi + a * 16 + orow;
#pragma unroll
            for (int b = 0; b < 4; ++b) {
                int j = j0 + wj + b * 16 + fr;
#pragma unroll
                for (int r = 0; r < 4; ++r)
                    D[(size_t)(ibx + r) * C_DIM + j] = __float2bfloat16(acc[a][b][r]);
            }
        }
    } else {
        // transposed store: Vp[(j0+jj)*N_PIX + (i0+ii)] via padded-LDS transpose
        __hip_bfloat16* Dvp = Vp + (size_t)bz * sNC;
        float bvb[4];
#pragma unroll
        for (int b = 0; b < 4; ++b)
            bvb[b] = bovp[j0 + wj + b * 16 + fr];
        __syncthreads();
        __hip_bfloat16* Tt = (__hip_bfloat16*)&As[0][0];   // [128][65] bf16
#pragma unroll
        for (int h = 0; h < 2; ++h) {
            if ((wave & 1) == h) {
#pragma unroll
                for (int a = 0; a < 4; ++a) {
                    int rl = wi + a * 16 + orow;
#pragma unroll
                    for (int b = 0; b < 4; ++b) {
                        int cl = b * 16 + fr;
#pragma unroll
                        for (int r = 0; r < 4; ++r)
                            Tt[(rl + r) * 65 + cl] =
                                __float2bfloat16(acc[a][b][r] + bvb[b]);
                    }
                }
            }
            __syncthreads();
            {
                const int lj = tid >> 2, ic = (tid & 3) * 32;
                union { __hip_bfloat16 h8[32]; int4 v4[4]; } u;
#pragma unroll
                for (int q = 0; q < 32; ++q)
                    u.h8[q] = Tt[(ic + q) * 65 + lj];
                __hip_bfloat16* dst = Dvp + (size_t)(j0 + h * 64 + lj) * N_PIX + i0 + ic;
#pragma unroll
                for (int q4 = 0; q4 < 4; ++q4)
                    ((int4*)dst)[q4] = u.v4[q4];
            }
            __syncthreads();
        }
    }
}

#undef PJ_STAGE
#undef PJ_COMP
#undef PJ_LOOP

// ---------------------------------------------------------------------------
// prep (grid 4713):
//   [0,16)     matT tiles: matT[c2][c1]=sum_o Wk[o,c2]Wq[o,c1]  (fp32-direct)
//   [16,32)    Wov tiles:  Wov[o][c]  =sum_o2 Wo[o,o2]Wv[o2,c]  (fp32-direct)
//   [32,104)   v-blocks:   v[b,m]=sum_c glox[b,c,m]·wv[c], wv recomputed
//   [104]      bov[o] = Wo[o,:]·bv
//   [105,4713) input transpose+cast (z<8 locx->Xlt else glox->Xgt)
// ---------------------------------------------------------------------------
__global__ __launch_bounds__(256)
void prep(const float* __restrict__ locx, const float* __restrict__ glox,
          const float* __restrict__ Wq, const float* __restrict__ Wk,
          const float* __restrict__ Wv, const float* __restrict__ Wo,
          const float* __restrict__ bq, const float* __restrict__ bv,
          __hip_bfloat16* __restrict__ Xlt, __hip_bfloat16* __restrict__ Xgt,
          __hip_bfloat16* __restrict__ matT, __hip_bfloat16* __restrict__ Wov,
          float* __restrict__ vvec, float* __restrict__ bovbuf)
{
    __shared__ __align__(16) char shm[16640];
    const int lin = blockIdx.x;
    const int tid = threadIdx.x;

    if (lin < 32) {
        // 128x128 tile GEMM, K=512, BK=32, single-buffered, bf16 staged on the fly
        __hip_bfloat16* As = (__hip_bfloat16*)shm;            // [128][32]
        __hip_bfloat16* Bs = (__hip_bfloat16*)(shm + 8192);   // [128][32]
        const int m2 = lin >> 4;
        const int t2 = lin & 15;
        const int j0 = (t2 & 3) * 128;
        const int i0 = (t2 >> 2) * 128;

        const int lane = tid & 63;
        const int wave = tid >> 6;
        const int fr = lane & 15;
        const int fq = lane >> 4;
        const int sw2 = fr & 3;
        const int wi = (wave >> 1) * 64;
        const int wj = (wave & 1) * 64;

        f32x4 acc[4][4];
#pragma unroll
        for (int a = 0; a < 4; ++a)
#pragma unroll
            for (int b = 0; b < 4; ++b)
                acc[a][b] = (f32x4){0.f, 0.f, 0.f, 0.f};

        const float* SB = m2 ? Wv : Wq;   // B operand, transposed staging
        const int o_r = tid >> 3;          // 0..31 (o within chunk)
        const int cc0 = (tid & 7) * 16;    // col base

#pragma unroll 1
        for (int o0 = 0; o0 < 512; o0 += 32) {
            // ---- stage A ----
            if (m2 == 0) {
                // As[c][o] = Wk[o0+o][i0+c]  (transposed, swizzled scalar stores)
                const float* src = Wk + (size_t)(o0 + o_r) * 512 + i0 + cc0;
                float v[16];
#pragma unroll
                for (int q4 = 0; q4 < 4; ++q4) {
                    float4 f = *(const float4*)(src + q4 * 4);
                    v[q4 * 4 + 0] = f.x; v[q4 * 4 + 1] = f.y;
                    v[q4 * 4 + 2] = f.z; v[q4 * 4 + 3] = f.w;
                }
#pragma unroll
                for (int q = 0; q < 16; ++q) {
                    const int col = cc0 + q;
                    const int byt = col * 64 + ((((o_r >> 3) ^ (col & 3)) << 4))
                                  + (o_r & 7) * 2;
                    *(__hip_bfloat16*)((char*)As + byt) = __float2bfloat16(v[q]);
                }
            } else {
                // As[r][o2] = Wo[i0+r][o0+o2]  (direct, vectorized swizzled)
                const int r = tid >> 1;
#pragma unroll
                for (int s = 0; s < 2; ++s) {
                    const int cp = (tid & 1) * 2 + s;   // chunk 0..3
                    const float* src = Wo + (size_t)(i0 + r) * 512 + o0 + cp * 8;
                    float4 f0 = *(const float4*)(src);
                    float4 f1 = *(const float4*)(src + 4);
                    union { __hip_bfloat16 h[8]; int4 v4; } u;
                    u.h[0] = __float2bfloat16(f0.x); u.h[1] = __float2bfloat16(f0.y);
                    u.h[2] = __float2bfloat16(f0.z); u.h[3] = __float2bfloat16(f0.w);
                    u.h[4] = __float2bfloat16(f1.x); u.h[5] = __float2bfloat16(f1.y);
                    u.h[6] = __float2bfloat16(f1.z); u.h[7] = __float2bfloat16(f1.w);
                    *(int4*)(As + r * 32 + ((cp ^ (r & 3)) << 3)) = u.v4;
                }
            }
            // ---- stage B (transposed): Bs[c][o] = SB[o0+o][j0+c] ----
            {
                const float* src = SB + (size_t)(o0 + o_r) * 512 + j0 + cc0;
                float v[16];
#pragma unroll
                for (int q4 = 0; q4 < 4; ++q4) {
                    float4 f = *(const float4*)(src + q4 * 4);
                    v[q4 * 4 + 0] = f.x; v[q4 * 4 + 1] = f.y;
                    v[q4 * 4 + 2] = f.z; v[q4 * 4 + 3] = f.w;
                }
#pragma unroll
                for (int q = 0; q < 16; ++q) {
                    const int col = cc0 + q;
                    const int byt = col * 64 + ((((o_r >> 3) ^ (col & 3)) << 4))
                                  + (o_r & 7) * 2;
                    *(__hip_bfloat16*)((char*)Bs + byt) = __float2bfloat16(v[q]);
                }
            }
            __syncthreads();
            // ---- MFMA (K=32) ----
            bf16x8 af[4], bfm[4];
#pragma unroll
            for (int tt = 0; tt < 4; ++tt) {
                af[tt]  = *(const bf16x8*)(As + (wi + tt * 16 + fr) * 32
                                              + ((fq ^ sw2) << 3));
                bfm[tt] = *(const bf16x8*)(Bs + (wj + tt * 16 + fr) * 32
                                              + ((fq ^ sw2) << 3));
            }
#pragma unroll
            for (int a = 0; a < 4; ++a)
#pragma unroll
                for (int b = 0; b < 4; ++b)
                    acc[a][b] = __builtin_amdgcn_mfma_f32_16x16x32_bf16(
                        af[a], bfm[b], acc[a][b], 0, 0, 0);
            __syncthreads();
        }
        __hip_bfloat16* D = m2 ? Wov : matT;
        const int orow = fq * 4;
#pragma unroll
        for (int a = 0; a < 4; ++a) {
            int ibx = i0 + wi + a * 16 + orow;
#pragma unroll
            for (int b = 0; b < 4; ++b) {
                int j = j0 + wj + b * 16 + fr;
#pragma unroll
                for (int r = 0; r < 4; ++r)
                    D[(size_t)(ibx + r) * 512 + j] = __float2bfloat16(acc[a][b][r]);
            }
        }
    } else if (lin < 104) {
        // v-block: wv recompute (Wk L2-resident) + glox column dot (fp32)
        const int blk = lin - 32;
        const int b   = blk / 9;
        const int m0  = (blk % 9) * 256;
        float a0 = 0.f, a1 = 0.f;
        for (int o = 0; o < 512; ++o) {
            const float bb = bq[o];
            a0 += Wk[(size_t)o * 512 + tid] * bb;
            a1 += Wk[(size_t)o * 512 + tid + 256] * bb;
        }
        float* wvs = (float*)shm;
        wvs[tid] = a0;
        wvs[tid + 256] = a1;
        __syncthreads();
        const float* col = glox + (size_t)b * 512 * N_PIX + m0 + tid;
        float acc = 0.f;
        for (int c = 0; c < 512; ++c)
            acc += col[(size_t)c * N_PIX] * wvs[c];
        vvec[(size_t)b * N_PIX + m0 + tid] = acc;
    } else if (lin == 104) {
        // bov[o] = Wo[o,:]·bv
#pragma unroll
        for (int half = 0; half < 2; ++half) {
            int o = tid + half * 256;
            float acc = 0.f;
            for (int c4 = 0; c4 < 128; ++c4) {
                float4 f = *(const float4*)(Wo + (size_t)o * 512 + c4 * 4);
                float4 g = *(const float4*)(bv + c4 * 4);
                acc += f.x * g.x + f.y * g.y + f.z * g.z + f.w * g.w;
            }
            bovbuf[o] = acc;
        }
    } else {
        // input transpose+cast
        float* t = (float*)shm;                    // [64][65]
        const int lin2 = lin - 105;
        const int z  = lin2 & 15;
        const int t2 = lin2 >> 4;
        const int c0 = (t2 & 7) * 64;
        const int n0 = (t2 >> 3) * 64;
        const size_t b = z & 7;
        const float* Xb = ((z < 8) ? locx : glox) + b * (size_t)C_DIM * N_PIX;
        __hip_bfloat16* Xt = (z < 8) ? Xlt : Xgt;

        const int n_l = tid & 63;
        const int c_b = tid >> 6;
#pragma unroll
        for (int s = 0; s < 16; ++s) {
            int c_l = c_b + s * 4;
            t[c_l * 65 + n_l] = Xb[(size_t)(c0 + c_l) * N_PIX + n0 + n_l];
        }
        __syncthreads();

        const int cc = (tid & 7) * 8;
        const int nb = tid >> 3;
#pragma unroll
        for (int it = 0; it < 2; ++it) {
            int n2 = nb + it * 32;
            union { __hip_bfloat16 h[8]; int4 v; } u;
#pragma unroll
            for (int w = 0; w < 8; ++w)
                u.h[w] = __float2bfloat16(t[(cc + w) * 65 + n2]);
            *(int4*)(&Xt[(b * N_PIX + n0 + n2) * C_DIM + c0 + cc]) = u.v;
        }
    }
}

// ---------------------------------------------------------------------------
extern "C" void kernel_launch(void* const* d_in, const int* in_sizes, int n_in,
                              void* d_out, int out_size, void* d_ws, size_t ws_size,
                              hipStream_t stream)
{
    const float* locx = (const float*)d_in[0];
    const float* glox = (const float*)d_in[1];
    const float* Wq = (const float*)d_in[2];
    const float* bq = (const float*)d_in[3];
    const float* Wk = (const float*)d_in[4];
    const float* bk = (const float*)d_in[5];   // unused: u[n],c0 cancel in softmax
    const float* Wv = (const float*)d_in[6];
    const float* bv = (const float*)d_in[7];
    const float* Wo = (const float*)d_in[8];
    const float* bo = (const float*)d_in[9];
    float* out = (float*)d_out;
    (void)bk;

    const int C = C_DIM, N = N_PIX;
    const size_t WB   = (size_t)C * C * 2;             // 0.5 MB bf16 mat
    const size_t szX  = (size_t)N_BATCH * N * C * 2;   // 18.87 MB
    const size_t szP1 = (size_t)N * N * 2;
    const size_t szRP = (size_t)NJB * N_BATCH * N * 4;
    const size_t szV  = (size_t)N_BATCH * N * 4;       // vvec

    char* ws = (char*)d_ws;
    size_t off = 0;
    auto alloc = [&](size_t bytes) {
        char* p = ws + off;
        off += (bytes + 255) & ~(size_t)255;
        return p;
    };
    __hip_bfloat16* matT  = (__hip_bfloat16*)alloc(WB);
    __hip_bfloat16* Wov   = (__hip_bfloat16*)alloc(WB);
    float*          bovb  = (float*)alloc(512 * 4);
    float*          vvec  = (float*)alloc(szV);
    __hip_bfloat16* Xlt   = (__hip_bfloat16*)alloc(szX);
    __hip_bfloat16* Xgt   = (__hip_bfloat16*)alloc(szX);
    __hip_bfloat16* Tm    = (__hip_bfloat16*)alloc(szX);
    __hip_bfloat16* Vp    = (__hip_bfloat16*)alloc(szX);
    float*          rp    = (float*)alloc(szRP);
    const size_t fixed = off;
    bool full = (ws_size >= fixed + 8 * szP1 + 4096);
    __hip_bfloat16* Pu = (__hip_bfloat16*)alloc(full ? 8 * szP1 : szP1);

    const dim3 blk(256);

    prep<<<dim3(4713), blk, 0, stream>>>(locx, glox, Wq, Wk, Wv, Wo, bq, bv,
                                         Xlt, Xgt, matT, Wov, vvec, bovb);
    proj2<<<dim3(16 * 72), blk, 0, stream>>>(Xlt, Xgt, matT, Wov, bovb, Tm, Vp);

    if (full) {
        s_only<8><<<dim3(8 * 81), dim3(512), 0, stream>>>(
            Tm, Xgt, Pu, rp, vvec, 0, (long)N * N);
        pv_out<8><<<dim3(8 * 72), blk, 0, stream>>>(
            Vp, Pu, out, bo, rp, 0, (long)N * N);
    } else {
        for (int r = 0; r < N_BATCH; ++r) {
            s_only<1><<<dim3(81), dim3(512), 0, stream>>>(
                Tm, Xgt, Pu, rp, vvec, r, 0);
            pv_out<1><<<dim3(72), blk, 0, stream>>>(
                Vp, Pu, out, bo, rp, r, 0);
        }
    }
}

// Round 9
// 329.459 us; speedup vs baseline: 1.1115x; 1.0636x over previous
//
#include <hip/hip_runtime.h>
#include <hip/hip_bf16.h>

typedef __attribute__((ext_vector_type(4))) float f32x4;
typedef __attribute__((ext_vector_type(8))) short bf16x8;
typedef __attribute__((ext_vector_type(4))) short s16x4;

#define C_DIM 512
#define N_PIX 2304
#define N_BATCH 8
#define ATT_SCALE 0.04419417382415922f
#define NJB 9                       // N_PIX / 256 (s-kernel j-tiles)

typedef __attribute__((address_space(3))) unsigned int lds_u32;
typedef const __attribute__((address_space(1))) unsigned int glob_u32;

__device__ __forceinline__ void gl2lds16(const __hip_bfloat16* g, __hip_bfloat16* l)
{
    __builtin_amdgcn_global_load_lds((glob_u32*)g, (lds_u32*)l, 16, 0, 0);
}

#define GBAR() __builtin_amdgcn_s_barrier()
#define GVM0() asm volatile("s_waitcnt vmcnt(0)" ::: "memory")
#define GVM6() asm volatile("s_waitcnt vmcnt(6)" ::: "memory")
#define GVM8() asm volatile("s_waitcnt vmcnt(8)" ::: "memory")

// ===========================================================================
// ALGEBRAIC FOLDS (round-6/7, kept):
//  scores/sc = Xl·(Wq^T Wk)·Xg^T + v[m]  (row-constant terms cancel in softmax)
//  Vp = (Wo·Wv)·Xg^T + bov
// ROUND-9: pv_out = 64x128 tile (48KB LDS -> 3 blocks/CU, 1152 blocks) WITH
// the round-8 2-deep counted pipeline (vmcnt(6): 6 gl2lds/wave per STAGE).
// Round-8's 128^2 counted pv ran at 1 block/CU (occ 12%) -> nothing hid the
// per-wave ds_read chain; 64x128 restores cross-block overlap.
// ===========================================================================

// ---------------------------------------------------------------------------
// s_only: 256x256 8-phase (round-1-proven structure), S-tiles only (648 blks).
// Pu[n,m] = exp(SC*(sum_c T[n,c]Xgt[m,c] + v[m])), rp row-sum partials.
// ---------------------------------------------------------------------------

#define BAR()  __builtin_amdgcn_s_barrier()
#define LGK0() asm volatile("s_waitcnt lgkmcnt(0)" ::: "memory")
#define VM4()  asm volatile("s_waitcnt vmcnt(4)" ::: "memory")
#define VM0()  asm volatile("s_waitcnt vmcnt(0)" ::: "memory")
#define PRIO(p) __builtin_amdgcn_s_setprio(p)

#define STAGE_A(dd, hh, tk) do { \
    _Pragma("unroll") \
    for (int ss = 0; ss < 2; ++ss) { \
        const int ur0 = wave * 16 + ss * 8; \
        const int row0 = ((ur0 >> 6) << 7) + (hh) * 64 + (ur0 & 63); \
        gl2lds16(gA + (size_t)row0 * C_DIM + (tk) * 64, \
                 (__hip_bfloat16*)&LA[dd][row0 * 64]); \
    } } while (0)

#define STAGE_B(dd, bb, tk) do { \
    _Pragma("unroll") \
    for (int ss = 0; ss < 2; ++ss) { \
        const int ur0 = wave * 16 + ss * 8; \
        const int row0 = ((ur0 >> 5) << 6) + (bb) * 32 + (ur0 & 31); \
        gl2lds16(gB + (size_t)row0 * C_DIM + (tk) * 64, \
                 (__hip_bfloat16*)&LB[dd][row0 * 64]); \
    } } while (0)

#define LOAD_A(dd, hh) do { \
    _Pragma("unroll") \
    for (int tt = 0; tt < 4; ++tt) { \
        const int rb = (wr * 128 + (hh) * 64 + tt * 16 + fr) * 64; \
        _Pragma("unroll") \
        for (int kk = 0; kk < 2; ++kk) \
            aF[tt][kk] = *(const bf16x8*)(&LA[dd][rb + (((kk * 4 + fq) ^ sw) << 3)]); \
    } } while (0)

#define LOAD_B(dd, bb, dst) do { \
    _Pragma("unroll") \
    for (int s2 = 0; s2 < 2; ++s2) { \
        const int rb = (wc * 64 + (bb) * 32 + s2 * 16 + fr) * 64; \
        _Pragma("unroll") \
        for (int kk = 0; kk < 2; ++kk) \
            dst[s2][kk] = *(const bf16x8*)(&LB[dd][rb + (((kk * 4 + fq) ^ sw) << 3)]); \
    } } while (0)

#define MFMA_Q(HH, BB, bsrc) do { \
    _Pragma("unroll") \
    for (int tt = 0; tt < 4; ++tt) \
    _Pragma("unroll") \
    for (int s2 = 0; s2 < 2; ++s2) \
    _Pragma("unroll") \
    for (int kk = 0; kk < 2; ++kk) \
        acc[(HH) * 4 + tt][(BB) * 2 + s2] = __builtin_amdgcn_mfma_f32_16x16x32_bf16( \
            aF[tt][kk], bsrc[s2][kk], acc[(HH) * 4 + tt][(BB) * 2 + s2], 0, 0, 0); \
    } while (0)

template<int NS>
__global__ __launch_bounds__(512, 2)
void s_only(const __hip_bfloat16* __restrict__ Tm, const __hip_bfloat16* __restrict__ Xgt,
            __hip_bfloat16* __restrict__ Pu, float* __restrict__ rp,
            const float* __restrict__ vvec, int bz_off, long sPu)
{
    __shared__ __hip_bfloat16 LA[2][256 * 64];
    __shared__ __hip_bfloat16 LB[2][256 * 64];

    const int lin = blockIdx.x;
    const int bz  = lin % NS + bz_off;
    const int t   = lin / NS;
    const int ib  = t / 9;
    const int jb  = t % 9;
    const long sQ = (long)N_PIX * C_DIM;

    const __hip_bfloat16* A = Tm  + (size_t)bz * sQ;
    const __hip_bfloat16* B = Xgt + (size_t)bz * sQ;
    __hip_bfloat16* D = Pu + (size_t)bz * (size_t)sPu;

    const int i0 = ib * 256;
    const int j0 = jb * 256;

    const int tid  = threadIdx.x;
    const int lane = tid & 63;
    const int wave = tid >> 6;

    const int lrow = lane >> 3;
    const int lcs  = (lane & 7) ^ lrow;           // XOR chunk swizzle (store side)
    const __hip_bfloat16* gA = A + (size_t)(i0 + lrow) * C_DIM + lcs * 8;
    const __hip_bfloat16* gB = B + (size_t)(j0 + lrow) * C_DIM + lcs * 8;

    const int fr = lane & 15;
    const int fq = lane >> 4;
    const int sw = fr & 7;                        // row&7 on read side
    const int wr = wave >> 2;                     // 0..1 (row wave)
    const int wc = wave & 3;                      // 0..3 (col wave)

    f32x4 acc[8][4];
#pragma unroll
    for (int a = 0; a < 8; ++a)
#pragma unroll
        for (int b = 0; b < 4; ++b)
            acc[a][b] = (f32x4){0.f, 0.f, 0.f, 0.f};

    bf16x8 aF[4][2], bF0[2][2], bF1[2][2];

    // prologue: tile0 (4 halves) + tile1 {A0,B1}; vmcnt(4) -> tile0 landed
    STAGE_A(0, 0, 0); STAGE_B(0, 0, 0); STAGE_B(0, 1, 0); STAGE_A(0, 1, 0);
    STAGE_A(1, 0, 1); STAGE_B(1, 1, 1);
    VM4();
    BAR();

    for (int kt = 0; kt < 6; ++kt) {
        const int d = kt & 1, e = d ^ 1;
        LOAD_A(d, 0); LOAD_B(d, 0, bF0);
        STAGE_A(e, 1, kt + 1);
        BAR(); LGK0();
        PRIO(1); MFMA_Q(0, 0, bF0); PRIO(0);
        BAR();
        LOAD_B(d, 1, bF1);
        STAGE_B(e, 0, kt + 1);
        BAR(); LGK0();
        PRIO(1); MFMA_Q(0, 1, bF1); PRIO(0);
        BAR();
        LOAD_A(d, 1);
        STAGE_A(d, 0, kt + 2);
        BAR(); LGK0();
        PRIO(1); MFMA_Q(1, 1, bF1); PRIO(0);
        BAR();
        STAGE_B(d, 1, kt + 2);
        VM4();
        BAR();
        PRIO(1); MFMA_Q(1, 0, bF0); PRIO(0);
        BAR();
    }
    {   // K-tile 6 (buf 0): stage only tile-7 {A1,B0}
        LOAD_A(0, 0); LOAD_B(0, 0, bF0);
        STAGE_A(1, 1, 7);
        BAR(); LGK0();
        PRIO(1); MFMA_Q(0, 0, bF0); PRIO(0);
        BAR();
        LOAD_B(0, 1, bF1);
        STAGE_B(1, 0, 7);
        BAR(); LGK0();
        PRIO(1); MFMA_Q(0, 1, bF1); PRIO(0);
        BAR();
        LOAD_A(0, 1);
        BAR(); LGK0();
        PRIO(1); MFMA_Q(1, 1, bF1); PRIO(0);
        BAR();
        VM0();
        BAR();
        PRIO(1); MFMA_Q(1, 0, bF0); PRIO(0);
        BAR();
    }
    {   // K-tile 7 (buf 1): no staging
        LOAD_A(1, 0); LOAD_B(1, 0, bF0);
        BAR(); LGK0();
        PRIO(1); MFMA_Q(0, 0, bF0); PRIO(0);
        BAR();
        LOAD_B(1, 1, bF1);
        BAR(); LGK0();
        PRIO(1); MFMA_Q(0, 1, bF1); PRIO(0);
        BAR();
        LOAD_A(1, 1);
        BAR(); LGK0();
        PRIO(1); MFMA_Q(1, 1, bF1); PRIO(0);
        BAR();
        PRIO(1); MFMA_Q(1, 0, bF0); PRIO(0);
    }

    // epilogue: exp(SC*(acc + v[m])), rp partials
    float vb[4];
#pragma unroll
    for (int b = 0; b < 4; ++b)
        vb[b] = vvec[(size_t)bz * N_PIX + j0 + wc * 64 + b * 16 + fr];

    float rpart[8][4];
#pragma unroll
    for (int a = 0; a < 8; ++a)
#pragma unroll
        for (int r = 0; r < 4; ++r)
            rpart[a][r] = 0.f;
#pragma unroll
    for (int a = 0; a < 8; ++a) {
        const int grow = i0 + wr * 128 + a * 16 + fq * 4;
#pragma unroll
        for (int b = 0; b < 4; ++b) {
            const int col = j0 + wc * 64 + b * 16 + fr;
#pragma unroll
            for (int r = 0; r < 4; ++r) {
                float v = __expf(ATT_SCALE * (acc[a][b][r] + vb[b]));
                rpart[a][r] += v;
                D[(size_t)(grow + r) * N_PIX + col] = __float2bfloat16(v);
            }
        }
    }
#pragma unroll
    for (int m = 1; m < 16; m <<= 1)
#pragma unroll
        for (int a = 0; a < 8; ++a)
#pragma unroll
            for (int r = 0; r < 4; ++r)
                rpart[a][r] += __shfl_xor(rpart[a][r], m);
    float* rsl = (float*)&LA[0][0];
    __syncthreads();
    if (fr == 0) {
#pragma unroll
        for (int a = 0; a < 8; ++a)
#pragma unroll
            for (int r = 0; r < 4; ++r)
                rsl[wave * 128 + a * 16 + fq * 4 + r] = rpart[a][r];
    }
    __syncthreads();
    if (tid < 256) {
        const int wr2 = tid >> 7, rl = tid & 127;
        float s = rsl[(wr2 * 4 + 0) * 128 + rl] + rsl[(wr2 * 4 + 1) * 128 + rl]
                + rsl[(wr2 * 4 + 2) * 128 + rl] + rsl[(wr2 * 4 + 3) * 128 + rl];
        rp[((size_t)jb * N_BATCH + bz) * N_PIX + i0 + tid] = s;
    }
}

#undef STAGE_A
#undef STAGE_B
#undef LOAD_A
#undef LOAD_B
#undef MFMA_Q
#undef BAR
#undef LGK0
#undef VM4
#undef VM0
#undef PRIO

// ---------------------------------------------------------------------------
// PV + output, ROUND-9: 64x128 tile (48KB LDS, 3 blocks/CU, grid NS*144
// i-fast) + 2-deep counted pipeline (vmcnt(6): 6 gl2lds/wave per STAGE).
// out[o,n] = rinv[n]*sum_m Vp[o,m]Pu[n,m] + bo[o]. 36 K-tiles.
// ---------------------------------------------------------------------------

#define PV_STAGE(ee, tk) do { \
    _Pragma("unroll") \
    for (int ss = 0; ss < 2; ++ss) \
        gl2lds16(ga + (size_t)ss * 8 * N_PIX + (tk) * 64, \
                 laA + (ee) * (64 * 64) + ss * 8 * 64); \
    _Pragma("unroll") \
    for (int ss = 0; ss < 4; ++ss) \
        gl2lds16(gb + (size_t)ss * 8 * N_PIX + (tk) * 64, \
                 laB + (ee) * (128 * 64) + ss * 8 * 64); \
    } while (0)

#define PV_COMP(dd) do { \
    _Pragma("unroll") \
    for (int kk = 0; kk < 2; ++kk) { \
        bf16x8 af[2], bfr[4]; \
        const int ca = ((kk * 4 + fq) ^ sw) << 3; \
        _Pragma("unroll") \
        for (int tt = 0; tt < 2; ++tt) \
            af[tt]  = *(const bf16x8*)(&As[dd][(wi + tt * 16 + fr) * 64 + ca]); \
        _Pragma("unroll") \
        for (int tt = 0; tt < 4; ++tt) \
            bfr[tt] = *(const bf16x8*)(&Bs[dd][(wj + tt * 16 + fr) * 64 + ca]); \
        _Pragma("unroll") \
        for (int a = 0; a < 2; ++a) \
        _Pragma("unroll") \
        for (int b = 0; b < 4; ++b) \
            acc[a][b] = __builtin_amdgcn_mfma_f32_16x16x32_bf16( \
                af[a], bfr[b], acc[a][b], 0, 0, 0); \
    } } while (0)

template<int NS>
__global__ __launch_bounds__(256)
void pv_out(const __hip_bfloat16* __restrict__ Vp, const __hip_bfloat16* __restrict__ Pu,
            float* __restrict__ out, const float* __restrict__ bo,
            const float* __restrict__ rp, int bz_off, long sPu)
{
    __shared__ __hip_bfloat16 As[2][64 * 64];
    __shared__ __hip_bfloat16 Bs[2][128 * 64];

    const int lin = blockIdx.x;
    const int bz  = lin % NS + bz_off;
    const int t   = lin / NS;
    const int ib  = t % 8;       // i-fast: consecutive blocks share Pu j-tile
    const int jb  = t / 8;
    const int i0  = ib * 64;
    const int j0  = jb * 128;

    const long sCN = (long)C_DIM * N_PIX;
    const __hip_bfloat16* A = Vp + (size_t)bz * sCN;         // [C,N] lda=N
    const __hip_bfloat16* B = Pu + (size_t)bz * (size_t)sPu; // [N,N] ldb=N
    float* D = out + (size_t)bz * sCN;

    const int tid  = threadIdx.x;
    const int lane = tid & 63;
    const int wave = tid >> 6;

    const int lrow = lane >> 3;
    const int lcs  = (lane & 7) ^ lrow;
    const __hip_bfloat16* ga = A + (size_t)(i0 + wave * 16 + lrow) * N_PIX + lcs * 8;
    const __hip_bfloat16* gb = B + (size_t)(j0 + wave * 32 + lrow) * N_PIX + lcs * 8;
    __hip_bfloat16* laA = &As[0][wave * 16 * 64];
    __hip_bfloat16* laB = &Bs[0][wave * 32 * 64];

    const int fr = lane & 15;
    const int fq = lane >> 4;
    const int sw = fr & 7;
    const int wi = (wave >> 1) * 32;
    const int wj = (wave & 1) * 64;

    f32x4 acc[2][4];
#pragma unroll
    for (int a = 0; a < 2; ++a)
#pragma unroll
        for (int b = 0; b < 4; ++b)
            acc[a][b] = (f32x4){0.f, 0.f, 0.f, 0.f};

    // prologue: 2 tiles in flight (12 loads/wave outstanding)
    PV_STAGE(0, 0);
    PV_STAGE(1, 1);

    // main: tiles 0..33, stage kt+2 after the read-barrier
#pragma unroll 1
    for (int kt = 0; kt < 34; kt += 2) {
        GVM6();                 // tile kt landed; kt+1's 6 loads in flight
        GBAR();
        PV_COMP(0);
        GBAR();                 // all waves done reading buf0
        PV_STAGE(0, kt + 2);
        GVM6();                 // tile kt+1 landed; kt+2 in flight
        GBAR();
        PV_COMP(1);
        GBAR();
        PV_STAGE(1, kt + 3);
    }
    // tail: tiles 34 (buf0), 35 (buf1); no more staging
    GVM6();
    GBAR();
    PV_COMP(0);
    GVM0();                     // tile 35 landed
    GBAR();
    PV_COMP(1);

    const int orow = fq * 4;
    float rjv[4];
#pragma unroll
    for (int b = 0; b < 4; ++b) {
        int j = j0 + wj + b * 16 + fr;
        float s = 0.f;
#pragma unroll
        for (int jj = 0; jj < NJB; ++jj)
            s += rp[((size_t)jj * N_BATCH + bz) * N_PIX + j];
        rjv[b] = 1.f / s;
    }

#pragma unroll
    for (int a = 0; a < 2; ++a) {
        int ibx = i0 + wi + a * 16 + orow;
#pragma unroll
        for (int r = 0; r < 4; ++r) {
            float bi = bo[ibx + r];
#pragma unroll
            for (int b = 0; b < 4; ++b) {
                int j = j0 + wj + b * 16 + fr;
                D[(size_t)(ibx + r) * N_PIX + j] = acc[a][b][r] * rjv[b] + bi;
            }
        }
    }
}

#undef PV_STAGE
#undef PV_COMP

// ---------------------------------------------------------------------------
// 128x128 K=512 GEMM machinery (round-8, counted vmcnt(8) pipeline).
// ---------------------------------------------------------------------------

#define PJ_STAGE(ee, tk) do { \
    _Pragma("unroll") \
    for (int ss = 0; ss < 4; ++ss) { \
        gl2lds16(ga + (size_t)ss * 8 * C_DIM + (tk) * 64, \
                 laA + (ee) * (128 * 64) + ss * 8 * 64); \
        gl2lds16(gb + (size_t)ss * 8 * C_DIM + (tk) * 64, \
                 laB + (ee) * (128 * 64) + ss * 8 * 64); \
    } } while (0)

#define PJ_COMP(dd) do { \
    _Pragma("unroll") \
    for (int kk = 0; kk < 2; ++kk) { \
        bf16x8 af[4], bfr[4]; \
        const int ca = ((kk * 4 + fq) ^ sw) << 3; \
        _Pragma("unroll") \
        for (int tt = 0; tt < 4; ++tt) { \
            af[tt]  = *(const bf16x8*)(&As[dd][(wi + tt * 16 + fr) * 64 + ca]); \
            bfr[tt] = *(const bf16x8*)(&Bs[dd][(wj + tt * 16 + fr) * 64 + ca]); \
        } \
        _Pragma("unroll") \
        for (int a = 0; a < 4; ++a) \
        _Pragma("unroll") \
        for (int b = 0; b < 4; ++b) \
            acc[a][b] = __builtin_amdgcn_mfma_f32_16x16x32_bf16( \
                af[a], bfr[b], acc[a][b], 0, 0, 0); \
    } } while (0)

#define PJ_LOOP() do { \
    PJ_STAGE(0, 0); \
    PJ_STAGE(1, 1); \
    _Pragma("unroll 1") \
    for (int kt = 0; kt < 6; kt += 2) { \
        GVM8(); GBAR(); \
        PJ_COMP(0); \
        GBAR(); \
        PJ_STAGE(0, kt + 2); \
        GVM8(); GBAR(); \
        PJ_COMP(1); \
        GBAR(); \
        PJ_STAGE(1, kt + 3); \
    } \
    GVM8(); GBAR(); \
    PJ_COMP(0); \
    GVM0(); GBAR(); \
    PJ_COMP(1); \
    } while (0)

// ---------------------------------------------------------------------------
// proj2: mat0: T = gemm_bt(Xlt, matT)   (no bias, standard [n,c] store)
//        mat1: Vp = gemm_bt(Xgt, Wov)+bov, stored TRANSPOSED [o,m] via LDS.
// Grid 16 x 72 = 1152.
// ---------------------------------------------------------------------------
__global__ __launch_bounds__(256)
void proj2(const __hip_bfloat16* __restrict__ Xlt,
           const __hip_bfloat16* __restrict__ Xgt,
           const __hip_bfloat16* __restrict__ matT,
           const __hip_bfloat16* __restrict__ Wov,
           const float* __restrict__ bovp,
           __hip_bfloat16* __restrict__ Tm,
           __hip_bfloat16* __restrict__ Vp)
{
    __shared__ __hip_bfloat16 As[2][128 * 64];
    __shared__ __hip_bfloat16 Bs[2][128 * 64];

    const int lin = blockIdx.x;
    const int s   = lin % 16;
    const int bz  = s & 7;
    const int m2  = s >> 3;
    const int t2  = lin / 16;
    const int j0  = (t2 & 3) * 128;
    const int i0  = (t2 >> 2) * 128;
    const long sNC = (long)N_PIX * C_DIM;

    const __hip_bfloat16* Ab = (m2 ? Xgt : Xlt) + (size_t)bz * sNC;
    const __hip_bfloat16* Bb = m2 ? Wov : matT;

    const int tid  = threadIdx.x;
    const int lane = tid & 63;
    const int wave = tid >> 6;

    const int lrow = lane >> 3;
    const int lcs  = (lane & 7) ^ lrow;
    const __hip_bfloat16* ga = Ab + (size_t)(i0 + wave * 32 + lrow) * C_DIM + lcs * 8;
    const __hip_bfloat16* gb = Bb + (size_t)(j0 + wave * 32 + lrow) * C_DIM + lcs * 8;
    __hip_bfloat16* laA = &As[0][wave * 32 * 64];
    __hip_bfloat16* laB = &Bs[0][wave * 32 * 64];

    const int fr = lane & 15;
    const int fq = lane >> 4;
    const int sw = fr & 7;
    const int wi = (wave >> 1) * 64;
    const int wj = (wave & 1) * 64;

    f32x4 acc[4][4];
#pragma unroll
    for (int a = 0; a < 4; ++a)
#pragma unroll
        for (int b = 0; b < 4; ++b)
            acc[a][b] = (f32x4){0.f, 0.f, 0.f, 0.f};

    PJ_LOOP();

    const int orow = fq * 4;
    if (m2 == 0) {
        __hip_bfloat16* D = Tm + (size_t)bz * sNC;
#pragma unroll
        for (int a = 0; a < 4; ++a) {
            int ibx = i0 + wi + a * 16 + orow;
#pragma unroll
            for (int b = 0; b < 4; ++b) {
                int j = j0 + wj + b * 16 + fr;
#pragma unroll
                for (int r = 0; r < 4; ++r)
                    D[(size_t)(ibx + r) * C_DIM + j] = __float2bfloat16(acc[a][b][r]);
            }
        }
    } else {
        // transposed store: Vp[(j0+jj)*N_PIX + (i0+ii)] via padded-LDS transpose
        __hip_bfloat16* Dvp = Vp + (size_t)bz * sNC;
        float bvb[4];
#pragma unroll
        for (int b = 0; b < 4; ++b)
            bvb[b] = bovp[j0 + wj + b * 16 + fr];
        __syncthreads();
        __hip_bfloat16* Tt = (__hip_bfloat16*)&As[0][0];   // [128][65] bf16
#pragma unroll
        for (int h = 0; h < 2; ++h) {
            if ((wave & 1) == h) {
#pragma unroll
                for (int a = 0; a < 4; ++a) {
                    int rl = wi + a * 16 + orow;
#pragma unroll
                    for (int b = 0; b < 4; ++b) {
                        int cl = b * 16 + fr;
#pragma unroll
                        for (int r = 0; r < 4; ++r)
                            Tt[(rl + r) * 65 + cl] =
                                __float2bfloat16(acc[a][b][r] + bvb[b]);
                    }
                }
            }
            __syncthreads();
            {
                const int lj = tid >> 2, ic = (tid & 3) * 32;
                union { __hip_bfloat16 h8[32]; int4 v4[4]; } u;
#pragma unroll
                for (int q = 0; q < 32; ++q)
                    u.h8[q] = Tt[(ic + q) * 65 + lj];
                __hip_bfloat16* dst = Dvp + (size_t)(j0 + h * 64 + lj) * N_PIX + i0 + ic;
#pragma unroll
                for (int q4 = 0; q4 < 4; ++q4)
                    ((int4*)dst)[q4] = u.v4[q4];
            }
            __syncthreads();
        }
    }
}

#undef PJ_STAGE
#undef PJ_COMP
#undef PJ_LOOP

// ---------------------------------------------------------------------------
// prep (grid 4713):
//   [0,16)     matT tiles: matT[c2][c1]=sum_o Wk[o,c2]Wq[o,c1]  (fp32-direct)
//   [16,32)    Wov tiles:  Wov[o][c]  =sum_o2 Wo[o,o2]Wv[o2,c]  (fp32-direct)
//   [32,104)   v-blocks:   v[b,m]=sum_c glox[b,c,m]·wv[c], wv recomputed
//   [104]      bov[o] = Wo[o,:]·bv
//   [105,4713) input transpose+cast (z<8 locx->Xlt else glox->Xgt)
// ---------------------------------------------------------------------------
__global__ __launch_bounds__(256)
void prep(const float* __restrict__ locx, const float* __restrict__ glox,
          const float* __restrict__ Wq, const float* __restrict__ Wk,
          const float* __restrict__ Wv, const float* __restrict__ Wo,
          const float* __restrict__ bq, const float* __restrict__ bv,
          __hip_bfloat16* __restrict__ Xlt, __hip_bfloat16* __restrict__ Xgt,
          __hip_bfloat16* __restrict__ matT, __hip_bfloat16* __restrict__ Wov,
          float* __restrict__ vvec, float* __restrict__ bovbuf)
{
    __shared__ __align__(16) char shm[16640];
    const int lin = blockIdx.x;
    const int tid = threadIdx.x;

    if (lin < 32) {
        // 128x128 tile GEMM, K=512, BK=32, single-buffered, bf16 staged on the fly
        __hip_bfloat16* As = (__hip_bfloat16*)shm;            // [128][32]
        __hip_bfloat16* Bs = (__hip_bfloat16*)(shm + 8192);   // [128][32]
        const int m2 = lin >> 4;
        const int t2 = lin & 15;
        const int j0 = (t2 & 3) * 128;
        const int i0 = (t2 >> 2) * 128;

        const int lane = tid & 63;
        const int wave = tid >> 6;
        const int fr = lane & 15;
        const int fq = lane >> 4;
        const int sw2 = fr & 3;
        const int wi = (wave >> 1) * 64;
        const int wj = (wave & 1) * 64;

        f32x4 acc[4][4];
#pragma unroll
        for (int a = 0; a < 4; ++a)
#pragma unroll
            for (int b = 0; b < 4; ++b)
                acc[a][b] = (f32x4){0.f, 0.f, 0.f, 0.f};

        const float* SB = m2 ? Wv : Wq;   // B operand, transposed staging
        const int o_r = tid >> 3;          // 0..31 (o within chunk)
        const int cc0 = (tid & 7) * 16;    // col base

#pragma unroll 1
        for (int o0 = 0; o0 < 512; o0 += 32) {
            // ---- stage A ----
            if (m2 == 0) {
                // As[c][o] = Wk[o0+o][i0+c]  (transposed, swizzled scalar stores)
                const float* src = Wk + (size_t)(o0 + o_r) * 512 + i0 + cc0;
                float v[16];
#pragma unroll
                for (int q4 = 0; q4 < 4; ++q4) {
                    float4 f = *(const float4*)(src + q4 * 4);
                    v[q4 * 4 + 0] = f.x; v[q4 * 4 + 1] = f.y;
                    v[q4 * 4 + 2] = f.z; v[q4 * 4 + 3] = f.w;
                }
#pragma unroll
                for (int q = 0; q < 16; ++q) {
                    const int col = cc0 + q;
                    const int byt = col * 64 + ((((o_r >> 3) ^ (col & 3)) << 4))
                                  + (o_r & 7) * 2;
                    *(__hip_bfloat16*)((char*)As + byt) = __float2bfloat16(v[q]);
                }
            } else {
                // As[r][o2] = Wo[i0+r][o0+o2]  (direct, vectorized swizzled)
                const int r = tid >> 1;
#pragma unroll
                for (int s = 0; s < 2; ++s) {
                    const int cp = (tid & 1) * 2 + s;   // chunk 0..3
                    const float* src = Wo + (size_t)(i0 + r) * 512 + o0 + cp * 8;
                    float4 f0 = *(const float4*)(src);
                    float4 f1 = *(const float4*)(src + 4);
                    union { __hip_bfloat16 h[8]; int4 v4; } u;
                    u.h[0] = __float2bfloat16(f0.x); u.h[1] = __float2bfloat16(f0.y);
                    u.h[2] = __float2bfloat16(f0.z); u.h[3] = __float2bfloat16(f0.w);
                    u.h[4] = __float2bfloat16(f1.x); u.h[5] = __float2bfloat16(f1.y);
                    u.h[6] = __float2bfloat16(f1.z); u.h[7] = __float2bfloat16(f1.w);
                    *(int4*)(As + r * 32 + ((cp ^ (r & 3)) << 3)) = u.v4;
                }
            }
            // ---- stage B (transposed): Bs[c][o] = SB[o0+o][j0+c] ----
            {
                const float* src = SB + (size_t)(o0 + o_r) * 512 + j0 + cc0;
                float v[16];
#pragma unroll
                for (int q4 = 0; q4 < 4; ++q4) {
                    float4 f = *(const float4*)(src + q4 * 4);
                    v[q4 * 4 + 0] = f.x; v[q4 * 4 + 1] = f.y;
                    v[q4 * 4 + 2] = f.z; v[q4 * 4 + 3] = f.w;
                }
#pragma unroll
                for (int q = 0; q < 16; ++q) {
                    const int col = cc0 + q;
                    const int byt = col * 64 + ((((o_r >> 3) ^ (col & 3)) << 4))
                                  + (o_r & 7) * 2;
                    *(__hip_bfloat16*)((char*)Bs + byt) = __float2bfloat16(v[q]);
                }
            }
            __syncthreads();
            // ---- MFMA (K=32) ----
            bf16x8 af[4], bfm[4];
#pragma unroll
            for (int tt = 0; tt < 4; ++tt) {
                af[tt]  = *(const bf16x8*)(As + (wi + tt * 16 + fr) * 32
                                              + ((fq ^ sw2) << 3));
                bfm[tt] = *(const bf16x8*)(Bs + (wj + tt * 16 + fr) * 32
                                              + ((fq ^ sw2) << 3));
            }
#pragma unroll
            for (int a = 0; a < 4; ++a)
#pragma unroll
                for (int b = 0; b < 4; ++b)
                    acc[a][b] = __builtin_amdgcn_mfma_f32_16x16x32_bf16(
                        af[a], bfm[b], acc[a][b], 0, 0, 0);
            __syncthreads();
        }
        __hip_bfloat16* D = m2 ? Wov : matT;
        const int orow = fq * 4;
#pragma unroll
        for (int a = 0; a < 4; ++a) {
            int ibx = i0 + wi + a * 16 + orow;
#pragma unroll
            for (int b = 0; b < 4; ++b) {
                int j = j0 + wj + b * 16 + fr;
#pragma unroll
                for (int r = 0; r < 4; ++r)
                    D[(size_t)(ibx + r) * 512 + j] = __float2bfloat16(acc[a][b][r]);
            }
        }
    } else if (lin < 104) {
        // v-block: wv recompute (Wk L2-resident) + glox column dot (fp32)
        const int blk = lin - 32;
        const int b   = blk / 9;
        const int m0  = (blk % 9) * 256;
        float a0 = 0.f, a1 = 0.f;
        for (int o = 0; o < 512; ++o) {
            const float bb = bq[o];
            a0 += Wk[(size_t)o * 512 + tid] * bb;
            a1 += Wk[(size_t)o * 512 + tid + 256] * bb;
        }
        float* wvs = (float*)shm;
        wvs[tid] = a0;
        wvs[tid + 256] = a1;
        __syncthreads();
        const float* col = glox + (size_t)b * 512 * N_PIX + m0 + tid;
        float acc = 0.f;
        for (int c = 0; c < 512; ++c)
            acc += col[(size_t)c * N_PIX] * wvs[c];
        vvec[(size_t)b * N_PIX + m0 + tid] = acc;
    } else if (lin == 104) {
        // bov[o] = Wo[o,:]·bv
#pragma unroll
        for (int half = 0; half < 2; ++half) {
            int o = tid + half * 256;
            float acc = 0.f;
            for (int c4 = 0; c4 < 128; ++c4) {
                float4 f = *(const float4*)(Wo + (size_t)o * 512 + c4 * 4);
                float4 g = *(const float4*)(bv + c4 * 4);
                acc += f.x * g.x + f.y * g.y + f.z * g.z + f.w * g.w;
            }
            bovbuf[o] = acc;
        }
    } else {
        // input transpose+cast
        float* t = (float*)shm;                    // [64][65]
        const int lin2 = lin - 105;
        const int z  = lin2 & 15;
        const int t2 = lin2 >> 4;
        const int c0 = (t2 & 7) * 64;
        const int n0 = (t2 >> 3) * 64;
        const size_t b = z & 7;
        const float* Xb = ((z < 8) ? locx : glox) + b * (size_t)C_DIM * N_PIX;
        __hip_bfloat16* Xt = (z < 8) ? Xlt : Xgt;

        const int n_l = tid & 63;
        const int c_b = tid >> 6;
#pragma unroll
        for (int s = 0; s < 16; ++s) {
            int c_l = c_b + s * 4;
            t[c_l * 65 + n_l] = Xb[(size_t)(c0 + c_l) * N_PIX + n0 + n_l];
        }
        __syncthreads();

        const int cc = (tid & 7) * 8;
        const int nb = tid >> 3;
#pragma unroll
        for (int it = 0; it < 2; ++it) {
            int n2 = nb + it * 32;
            union { __hip_bfloat16 h[8]; int4 v; } u;
#pragma unroll
            for (int w = 0; w < 8; ++w)
                u.h[w] = __float2bfloat16(t[(cc + w) * 65 + n2]);
            *(int4*)(&Xt[(b * N_PIX + n0 + n2) * C_DIM + c0 + cc]) = u.v;
        }
    }
}

// ---------------------------------------------------------------------------
extern "C" void kernel_launch(void* const* d_in, const int* in_sizes, int n_in,
                              void* d_out, int out_size, void* d_ws, size_t ws_size,
                              hipStream_t stream)
{
    const float* locx = (const float*)d_in[0];
    const float* glox = (const float*)d_in[1];
    const float* Wq = (const float*)d_in[2];
    const float* bq = (const float*)d_in[3];
    const float* Wk = (const float*)d_in[4];
    const float* bk = (const float*)d_in[5];   // unused: u[n],c0 cancel in softmax
    const float* Wv = (const float*)d_in[6];
    const float* bv = (const float*)d_in[7];
    const float* Wo = (const float*)d_in[8];
    const float* bo = (const float*)d_in[9];
    float* out = (float*)d_out;
    (void)bk;

    const int C = C_DIM, N = N_PIX;
    const size_t WB   = (size_t)C * C * 2;             // 0.5 MB bf16 mat
    const size_t szX  = (size_t)N_BATCH * N * C * 2;   // 18.87 MB
    const size_t szP1 = (size_t)N * N * 2;
    const size_t szRP = (size_t)NJB * N_BATCH * N * 4;
    const size_t szV  = (size_t)N_BATCH * N * 4;       // vvec

    char* ws = (char*)d_ws;
    size_t off = 0;
    auto alloc = [&](size_t bytes) {
        char* p = ws + off;
        off += (bytes + 255) & ~(size_t)255;
        return p;
    };
    __hip_bfloat16* matT  = (__hip_bfloat16*)alloc(WB);
    __hip_bfloat16* Wov   = (__hip_bfloat16*)alloc(WB);
    float*          bovb  = (float*)alloc(512 * 4);
    float*          vvec  = (float*)alloc(szV);
    __hip_bfloat16* Xlt   = (__hip_bfloat16*)alloc(szX);
    __hip_bfloat16* Xgt   = (__hip_bfloat16*)alloc(szX);
    __hip_bfloat16* Tm    = (__hip_bfloat16*)alloc(szX);
    __hip_bfloat16* Vp    = (__hip_bfloat16*)alloc(szX);
    float*          rp    = (float*)alloc(szRP);
    const size_t fixed = off;
    bool full = (ws_size >= fixed + 8 * szP1 + 4096);
    __hip_bfloat16* Pu = (__hip_bfloat16*)alloc(full ? 8 * szP1 : szP1);

    const dim3 blk(256);

    prep<<<dim3(4713), blk, 0, stream>>>(locx, glox, Wq, Wk, Wv, Wo, bq, bv,
                                         Xlt, Xgt, matT, Wov, vvec, bovb);
    proj2<<<dim3(16 * 72), blk, 0, stream>>>(Xlt, Xgt, matT, Wov, bovb, Tm, Vp);

    if (full) {
        s_only<8><<<dim3(8 * 81), dim3(512), 0, stream>>>(
            Tm, Xgt, Pu, rp, vvec, 0, (long)N * N);
        pv_out<8><<<dim3(8 * 144), blk, 0, stream>>>(
            Vp, Pu, out, bo, rp, 0, (long)N * N);
    } else {
        for (int r = 0; r < N_BATCH; ++r) {
            s_only<1><<<dim3(81), dim3(512), 0, stream>>>(
                Tm, Xgt, Pu, rp, vvec, r, 0);
            pv_out<1><<<dim3(144), blk, 0, stream>>>(
                Vp, Pu, out, bo, rp, r, 0);
        }
    }
}